// Round 1
// baseline (1232.922 us; speedup 1.0000x reference)
//
#include <hip/hip_runtime.h>
#include <math.h>

#define BN_ 8
#define CIN 256
#define COUT 256
#define HH 64
#define WW 64
#define HW 4096
#define KK 9
#define EPS 1e-5f
#define NTOT (BN_ * COUT * HW)

// ws layout (floats):
//   off_ws: [B][KK][2][HW]   = 589824 floats (dy plane, dx plane per (b,kk))
//   wT:     [2304][COUT]     = 589824 floats  (wT[(c*9+kk)*256 + o] = w[o][c][kk])
//   stats:  [2][COUT]        = 512 floats (sum, sumsq)
#define OFF_WS 0
#define WT_WS  589824
#define ST_WS  1179648

// ---------------- Kernel A: offset conv (dy,dx per (b,kk,pixel)) ----------------
// grid (H, B, KK), block 64 (one wave = one image row). x rows staged in LDS.
__global__ __launch_bounds__(64) void offset_kernel(
    const float* __restrict__ x, const float* __restrict__ w_off,
    const float* __restrict__ b_off, float* __restrict__ off_ws) {
  const int t = threadIdx.x;     // w coordinate
  const int h = blockIdx.x;
  const int b = blockIdx.y;
  const int kk = blockIdx.z;
  __shared__ float s_x[3][WW + 2];
  const int q0 = kk * 2;
  float dy = b_off[q0], dx = b_off[q0 + 1];
  const float* xb = x + b * (CIN * HW);
  const float* w0 = w_off + q0 * (CIN * 9);
  const float* w1 = w_off + (q0 + 1) * (CIN * 9);
  for (int c = 0; c < CIN; ++c) {
    __syncthreads();
#pragma unroll
    for (int r = 0; r < 3; ++r) {
      int hh = h + r - 1;
      float v = 0.f;
      if (hh >= 0 && hh < HH) v = xb[c * HW + hh * WW + t];
      s_x[r][t + 1] = v;
      if (t == 0) { s_x[r][0] = 0.f; s_x[r][WW + 1] = 0.f; }
    }
    __syncthreads();
    float wa[9], wb[9];
#pragma unroll
    for (int u = 0; u < 9; ++u) { wa[u] = w0[c * 9 + u]; wb[u] = w1[c * 9 + u]; }
#pragma unroll
    for (int i = 0; i < 3; ++i)
#pragma unroll
      for (int j = 0; j < 3; ++j) {
        float v = s_x[i][t + j];
        dy = fmaf(v, wa[i * 3 + j], dy);
        dx = fmaf(v, wb[i * 3 + j], dx);
      }
  }
  const int p = h * WW + t;
  float* o = off_ws + ((b * KK + kk) * 2) * HW;
  o[p] = dy;
  o[HW + p] = dx;
}

// ---------------- Kernel W0: transpose w -> wT[(c*9+kk)][o] ----------------
// grid (64, 4): r-tile of 36 (=2304/64), o-tile of 64. LDS transpose.
__global__ __launch_bounds__(256) void wtrans_kernel(
    const float* __restrict__ w, float* __restrict__ wT) {
  __shared__ float s[64][37];
  const int o0 = blockIdx.y * 64;
  const int r0 = blockIdx.x * 36;
  const int t = threadIdx.x;
#pragma unroll
  for (int i = 0; i < 9; ++i) {
    int f = t + i * 256;           // 0..2303
    int oo = f / 36, rr = f - oo * 36;
    s[oo][rr] = w[(o0 + oo) * 2304 + r0 + rr];
  }
  __syncthreads();
#pragma unroll
  for (int i = 0; i < 9; ++i) {
    int f = t + i * 256;
    int rr = f >> 6, oo = f & 63;  // rr 0..35
    wT[(r0 + rr) * 256 + o0 + oo] = s[oo][rr];
  }
}

// ---------------- Kernel B: fused bilinear-gather implicit GEMM ----------------
// grid (512, 4): 64-pixel tile (one image row) x 64-cout tile. block 256.
#define BK 32
__global__ __launch_bounds__(256) void gemm_kernel(
    const float* __restrict__ x, const float* __restrict__ wT,
    const float* __restrict__ off_ws, const float* __restrict__ bias,
    float* __restrict__ out) {
  __shared__ float s_a[BK][64];
  __shared__ float s_b[BK][64];
  __shared__ float s_wt[4][64];
  __shared__ int   s_idx[4][64];
  const int t = threadIdx.x;
  const int n0 = blockIdx.x * 64;
  const int o0 = blockIdx.y * 64;
  const int b = n0 >> 12;
  const int p0 = n0 & (HW - 1);
  const float* xb = x + b * (CIN * HW);
  const int tx = t & 15, ty = t >> 4;
  float acc[4][4] = {{0.f}};

  for (int kk = 0; kk < KK; ++kk) {
    __syncthreads();
    if (t < 64) {
      const float* ob = off_ws + ((b * KK + kk) * 2) * HW + p0 + t;
      float dy = ob[0], dx = ob[HW];
      int p = p0 + t;
      int h = p >> 6, w = p & 63;
      float py = (float)(kk / 3 - 1 + h) + dy;
      float px = (float)(kk % 3 - 1 + w) + dx;
      float y0f = floorf(py), x0f = floorf(px);
      float fy = py - y0f, fx = px - x0f;
      int y0 = (int)y0f, x0 = (int)x0f;
      int y1 = y0 + 1, x1 = x0 + 1;
      bool vy0 = (y0 >= 0) && (y0 < HH), vy1 = (y1 >= 0) && (y1 < HH);
      bool vx0 = (x0 >= 0) && (x0 < WW), vx1 = (x1 >= 0) && (x1 < WW);
      int cy0 = min(max(y0, 0), HH - 1), cy1 = min(max(y1, 0), HH - 1);
      int cx0 = min(max(x0, 0), WW - 1), cx1 = min(max(x1, 0), WW - 1);
      s_idx[0][t] = cy0 * WW + cx0;  s_wt[0][t] = (vy0 && vx0) ? (1.f - fy) * (1.f - fx) : 0.f;
      s_idx[1][t] = cy0 * WW + cx1;  s_wt[1][t] = (vy0 && vx1) ? (1.f - fy) * fx : 0.f;
      s_idx[2][t] = cy1 * WW + cx0;  s_wt[2][t] = (vy1 && vx0) ? fy * (1.f - fx) : 0.f;
      s_idx[3][t] = cy1 * WW + cx1;  s_wt[3][t] = (vy1 && vx1) ? fy * fx : 0.f;
    }
    __syncthreads();

    for (int c0 = 0; c0 < CIN; c0 += BK) {
      __syncthreads();
      // stage A: wT rows (c0..c0+BK) x (o0..o0+63), coalesced float4
#pragma unroll
      for (int i = 0; i < 2; ++i) {
        int f = t + i * 256;             // 512 float4 total
        int kc = f >> 4;
        int o4 = (f & 15) << 2;
        float4 v = *(const float4*)(wT + ((c0 + kc) * KK + kk) * COUT + o0 + o4);
        *(float4*)&s_a[kc][o4] = v;
      }
      // stage B: bilinear-gathered sampled values
      {
        int px = t & 63;
        int cb = t >> 6;                 // 0..3
        int i0 = s_idx[0][px], i1 = s_idx[1][px], i2 = s_idx[2][px], i3 = s_idx[3][px];
        float q0 = s_wt[0][px], q1 = s_wt[1][px], q2 = s_wt[2][px], q3 = s_wt[3][px];
#pragma unroll
        for (int i = 0; i < 8; ++i) {
          int kc = cb * 8 + i;
          const float* xp = xb + (c0 + kc) * HW;
          float v = q0 * xp[i0] + q1 * xp[i1] + q2 * xp[i2] + q3 * xp[i3];
          s_b[kc][px] = v;
        }
      }
      __syncthreads();
#pragma unroll
      for (int kc = 0; kc < BK; ++kc) {
        float4 av = *(float4*)&s_a[kc][ty * 4];
        float4 bv = *(float4*)&s_b[kc][tx * 4];
        float a4[4] = {av.x, av.y, av.z, av.w};
        float b4[4] = {bv.x, bv.y, bv.z, bv.w};
#pragma unroll
        for (int i = 0; i < 4; ++i)
#pragma unroll
          for (int j = 0; j < 4; ++j)
            acc[i][j] = fmaf(a4[i], b4[j], acc[i][j]);
      }
    }
  }
  // epilogue: + bias, write
#pragma unroll
  for (int i = 0; i < 4; ++i) {
    int o = o0 + ty * 4 + i;
    float bv = bias[o];
    float4 r;
    r.x = acc[i][0] + bv; r.y = acc[i][1] + bv;
    r.z = acc[i][2] + bv; r.w = acc[i][3] + bv;
    *(float4*)(out + (b * COUT + o) * HW + p0 + tx * 4) = r;
  }
}

// ---------------- Kernel C: per-channel sum/sumsq ----------------
__global__ __launch_bounds__(256) void stats_kernel(
    const float* __restrict__ out, float* __restrict__ stats) {
  const int o = blockIdx.x, b = blockIdx.y;
  const float* p = out + (b * COUT + o) * HW;
  float s = 0.f, s2 = 0.f;
  for (int i = threadIdx.x * 4; i < HW; i += 1024) {
    float4 v = *(const float4*)(p + i);
    s += v.x + v.y + v.z + v.w;
    s2 += v.x * v.x + v.y * v.y + v.z * v.z + v.w * v.w;
  }
#pragma unroll
  for (int off = 32; off > 0; off >>= 1) {
    s += __shfl_down(s, off);
    s2 += __shfl_down(s2, off);
  }
  __shared__ float ps[4], ps2[4];
  int wid = threadIdx.x >> 6;
  if ((threadIdx.x & 63) == 0) { ps[wid] = s; ps2[wid] = s2; }
  __syncthreads();
  if (threadIdx.x == 0) {
    float t1 = ps[0] + ps[1] + ps[2] + ps[3];
    float t2 = ps2[0] + ps2[1] + ps2[2] + ps2[3];
    atomicAdd(&stats[o], t1);
    atomicAdd(&stats[COUT + o], t2);
  }
}

// ---------------- Kernel D: normalize + ReLU in-place ----------------
__global__ __launch_bounds__(256) void bn_kernel(
    float* __restrict__ out, const float* __restrict__ stats,
    const float* __restrict__ gamma, const float* __restrict__ beta) {
  int i4 = (blockIdx.x * 256 + threadIdx.x) * 4;
  int o = (i4 >> 12) & (COUT - 1);
  const float inv_n = 1.f / (float)(BN_ * HW);
  float mean = stats[o] * inv_n;
  float var = stats[COUT + o] * inv_n - mean * mean;
  float sc = gamma[o] * rsqrtf(var + EPS);
  float sh = beta[o] - mean * sc;
  float4 v = *(float4*)(out + i4);
  v.x = fmaxf(fmaf(v.x, sc, sh), 0.f);
  v.y = fmaxf(fmaf(v.y, sc, sh), 0.f);
  v.z = fmaxf(fmaf(v.z, sc, sh), 0.f);
  v.w = fmaxf(fmaf(v.w, sc, sh), 0.f);
  *(float4*)(out + i4) = v;
}

extern "C" void kernel_launch(void* const* d_in, const int* in_sizes, int n_in,
                              void* d_out, int out_size, void* d_ws, size_t ws_size,
                              hipStream_t stream) {
  const float* x     = (const float*)d_in[0];
  const float* w_off = (const float*)d_in[1];
  const float* b_off = (const float*)d_in[2];
  const float* w     = (const float*)d_in[3];
  const float* bias  = (const float*)d_in[4];
  const float* gamma = (const float*)d_in[5];
  const float* beta  = (const float*)d_in[6];
  float* out = (float*)d_out;
  float* ws = (float*)d_ws;
  float* off_ws = ws + OFF_WS;
  float* wT = ws + WT_WS;
  float* stats = ws + ST_WS;

  hipMemsetAsync(stats, 0, 2 * COUT * sizeof(float), stream);
  offset_kernel<<<dim3(HH, BN_, KK), 64, 0, stream>>>(x, w_off, b_off, off_ws);
  wtrans_kernel<<<dim3(64, 4), 256, 0, stream>>>(w, wT);
  gemm_kernel<<<dim3(512, 4), 256, 0, stream>>>(x, wT, off_ws, bias, out);
  stats_kernel<<<dim3(COUT, BN_), 256, 0, stream>>>(out, stats);
  bn_kernel<<<NTOT / 1024, 256, 0, stream>>>(out, stats, gamma, beta);
}

// Round 2
// 626.718 us; speedup vs baseline: 1.9673x; 1.9673x over previous
//
#include <hip/hip_runtime.h>
#include <math.h>

#define BN_ 8
#define CIN 256
#define COUT 256
#define HH 64
#define WW 64
#define HW 4096
#define KK 9
#define EPS 1e-5f
#define NTOT (BN_ * COUT * HW)

// ws layout (float units):
//   off_ws: [B][KK][2][HW]            = 589824 floats
//   wTb:    bf16 [72][256][40] shorts = 737280 shorts = 368640 floats
//           (wTb[kb][o][kc] = bf16(w[o][ (kb&7)*32+kc ][ kb>>3 ]), kc<32; pad kc 32..39)
//   stats:  [2][COUT]                 = 512 floats
#define OFF_WS 0
#define WTB_WS 589824
#define ST_WS  (589824 + 368640)

typedef float f32x4 __attribute__((ext_vector_type(4)));
typedef short s16x8 __attribute__((ext_vector_type(8)));

__device__ __forceinline__ unsigned short f2bf(float f) {
  unsigned int u = __float_as_uint(f);
  unsigned int r = (u + 0x7fffu + ((u >> 16) & 1u)) >> 16;  // RNE
  return (unsigned short)r;
}

// ---------------- Kernel A: offset conv (dy,dx per (b,kk,pixel)) ----------------
__global__ __launch_bounds__(64) void offset_kernel(
    const float* __restrict__ x, const float* __restrict__ w_off,
    const float* __restrict__ b_off, float* __restrict__ off_ws) {
  const int t = threadIdx.x;
  const int h = blockIdx.x;
  const int b = blockIdx.y;
  const int kk = blockIdx.z;
  __shared__ float s_x[3][WW + 2];
  const int q0 = kk * 2;
  float dy = b_off[q0], dx = b_off[q0 + 1];
  const float* xb = x + b * (CIN * HW);
  const float* w0 = w_off + q0 * (CIN * 9);
  const float* w1 = w_off + (q0 + 1) * (CIN * 9);
  for (int c = 0; c < CIN; ++c) {
    __syncthreads();
#pragma unroll
    for (int r = 0; r < 3; ++r) {
      int hh = h + r - 1;
      float v = 0.f;
      if (hh >= 0 && hh < HH) v = xb[c * HW + hh * WW + t];
      s_x[r][t + 1] = v;
      if (t == 0) { s_x[r][0] = 0.f; s_x[r][WW + 1] = 0.f; }
    }
    __syncthreads();
    float wa[9], wb[9];
#pragma unroll
    for (int u = 0; u < 9; ++u) { wa[u] = w0[c * 9 + u]; wb[u] = w1[c * 9 + u]; }
#pragma unroll
    for (int i = 0; i < 3; ++i)
#pragma unroll
      for (int j = 0; j < 3; ++j) {
        float v = s_x[i][t + j];
        dy = fmaf(v, wa[i * 3 + j], dy);
        dx = fmaf(v, wb[i * 3 + j], dx);
      }
  }
  const int p = h * WW + t;
  float* o = off_ws + ((b * KK + kk) * 2) * HW;
  o[p] = dy;
  o[HW + p] = dx;
}

// ---------------- Kernel W0: pack w -> bf16 fragment-friendly image ----------------
// grid 72 (one k-block of 32 channels each), block 256 (one thread per o).
__global__ __launch_bounds__(256) void wtrans_kernel(
    const float* __restrict__ w, unsigned short* __restrict__ wTb) {
  const int kb = blockIdx.x;          // 0..71 : kk*8 + cstep
  const int kk = kb >> 3;
  const int c0 = (kb & 7) << 5;
  const int o = threadIdx.x;
  unsigned short* dst = wTb + ((size_t)kb * 256 + o) * 40;
  const float* src = w + ((size_t)o * CIN + c0) * 9 + kk;
#pragma unroll
  for (int kc = 0; kc < 32; ++kc) dst[kc] = f2bf(src[kc * 9]);
#pragma unroll
  for (int kc = 32; kc < 40; ++kc) dst[kc] = 0;
}

// ---------------- Kernel B: fused bilinear-gather MFMA GEMM ----------------
// grid 512 (p-tiles of 64 = one image row), block 256 = 4 waves.
// Block computes out[b, 0..255, p0..p0+63]. Wave w handles o in [w*64, w*64+64).
__global__ __launch_bounds__(256) void gemm_kernel(
    const float* __restrict__ x, const unsigned short* __restrict__ wTb,
    const float* __restrict__ off_ws, const float* __restrict__ bias,
    float* __restrict__ out) {
  __shared__ unsigned short s_a[256 * 40];  // [o][kc] bf16, 80B row stride
  __shared__ unsigned short s_b[64 * 40];   // [p][kc] bf16
  __shared__ int   s_ix[4][64];
  __shared__ float s_qw[4][64];
  const int t = threadIdx.x;
  const int lane = t & 63;
  const int wv = t >> 6;                // wave id 0..3
  const int n0 = blockIdx.x * 64;
  const int b = n0 >> 12;
  const int p0 = n0 & (HW - 1);
  const float* xb = x + b * (CIN * HW);
  const int pg = t & 63;                // gather pixel
  const int chh = t >> 6;               // channel-half 0..3 (8 channels each)
  const int fr = lane & 15, fq = lane >> 4;

  f32x4 acc[4][4] = {};

  for (int kk = 0; kk < KK; ++kk) {
    __syncthreads();
    if (t < 64) {
      const float* ob = off_ws + ((size_t)(b * KK + kk) * 2) * HW + p0 + t;
      float dy = ob[0], dx = ob[HW];
      int p = p0 + t;
      int h = p >> 6, w_ = p & 63;
      float py = (float)(kk / 3 - 1 + h) + dy;
      float px = (float)(kk % 3 - 1 + w_) + dx;
      float y0f = floorf(py), x0f = floorf(px);
      float fy = py - y0f, fx = px - x0f;
      int y0 = (int)y0f, x0 = (int)x0f;
      int y1 = y0 + 1, x1 = x0 + 1;
      bool vy0 = (y0 >= 0) && (y0 < HH), vy1 = (y1 >= 0) && (y1 < HH);
      bool vx0 = (x0 >= 0) && (x0 < WW), vx1 = (x1 >= 0) && (x1 < WW);
      int cy0 = min(max(y0, 0), HH - 1), cy1 = min(max(y1, 0), HH - 1);
      int cx0 = min(max(x0, 0), WW - 1), cx1 = min(max(x1, 0), WW - 1);
      s_ix[0][t] = cy0 * WW + cx0;  s_qw[0][t] = (vy0 && vx0) ? (1.f - fy) * (1.f - fx) : 0.f;
      s_ix[1][t] = cy0 * WW + cx1;  s_qw[1][t] = (vy0 && vx1) ? (1.f - fy) * fx : 0.f;
      s_ix[2][t] = cy1 * WW + cx0;  s_qw[2][t] = (vy1 && vx0) ? fy * (1.f - fx) : 0.f;
      s_ix[3][t] = cy1 * WW + cx1;  s_qw[3][t] = (vy1 && vx1) ? fy * fx : 0.f;
    }

    for (int c0 = 0; c0 < CIN; c0 += 32) {
      __syncthreads();
      // ---- stage A: async copy 32 k-rows x 256 o (incl. pad) = 20480 B ----
      {
        const unsigned char* gb = (const unsigned char*)(wTb + ((size_t)(kk * 8 + (c0 >> 5)) * 256) * 40);
        unsigned char* lb = (unsigned char*)s_a;
#pragma unroll
        for (int i = 0; i < 5; ++i) {
          int chunk = (wv * 5 + i) * 1024;
          __builtin_amdgcn_global_load_lds(
              (const __attribute__((address_space(1))) unsigned char*)(gb + chunk + lane * 16),
              (__attribute__((address_space(3))) unsigned char*)(lb + chunk),
              16, 0, 0);
        }
      }
      // ---- stage B: bilinear gather -> bf16 ----
      {
        int i0 = s_ix[0][pg], i1 = s_ix[1][pg], i2 = s_ix[2][pg], i3 = s_ix[3][pg];
        float q0 = s_qw[0][pg], q1 = s_qw[1][pg], q2 = s_qw[2][pg], q3 = s_qw[3][pg];
        const float* xp = xb + (size_t)(c0 + chh * 8) * HW;
        s16x8 v;
#pragma unroll
        for (int i = 0; i < 8; ++i) {
          const float* xc = xp + (size_t)i * HW;
          float val = q0 * xc[i0] + q1 * xc[i1] + q2 * xc[i2] + q3 * xc[i3];
          v[i] = (short)f2bf(val);
        }
        *(s16x8*)&s_b[pg * 40 + chh * 8] = v;
      }
      __syncthreads();
      // ---- fragments + MFMA ----
      {
        s16x8 af[4], bf[4];
#pragma unroll
        for (int j = 0; j < 4; ++j)
          bf[j] = *(const s16x8*)&s_b[(j * 16 + fr) * 40 + fq * 8];
#pragma unroll
        for (int i = 0; i < 4; ++i)
          af[i] = *(const s16x8*)&s_a[(wv * 64 + i * 16 + fr) * 40 + fq * 8];
#pragma unroll
        for (int i = 0; i < 4; ++i)
#pragma unroll
          for (int j = 0; j < 4; ++j)
            acc[i][j] = __builtin_amdgcn_mfma_f32_16x16x32_bf16(af[i], bf[j], acc[i][j], 0, 0, 0);
      }
    }
  }
  // ---- epilogue: + bias, store fp32 ----
#pragma unroll
  for (int i = 0; i < 4; ++i) {
#pragma unroll
    for (int rg = 0; rg < 4; ++rg) {
      int o = wv * 64 + i * 16 + fq * 4 + rg;
      float bv = bias[o];
      float* op = out + ((size_t)(b * COUT + o)) * HW + p0 + fr;
#pragma unroll
      for (int j = 0; j < 4; ++j)
        op[j * 16] = acc[i][j][rg] + bv;
    }
  }
}

// ---------------- Kernel C: per-channel sum/sumsq ----------------
__global__ __launch_bounds__(256) void stats_kernel(
    const float* __restrict__ out, float* __restrict__ stats) {
  const int o = blockIdx.x, b = blockIdx.y;
  const float* p = out + ((size_t)(b * COUT + o)) * HW;
  float s = 0.f, s2 = 0.f;
  for (int i = threadIdx.x * 4; i < HW; i += 1024) {
    float4 v = *(const float4*)(p + i);
    s += v.x + v.y + v.z + v.w;
    s2 += v.x * v.x + v.y * v.y + v.z * v.z + v.w * v.w;
  }
#pragma unroll
  for (int off = 32; off > 0; off >>= 1) {
    s += __shfl_down(s, off);
    s2 += __shfl_down(s2, off);
  }
  __shared__ float ps[4], ps2[4];
  int wid = threadIdx.x >> 6;
  if ((threadIdx.x & 63) == 0) { ps[wid] = s; ps2[wid] = s2; }
  __syncthreads();
  if (threadIdx.x == 0) {
    atomicAdd(&stats[o], ps[0] + ps[1] + ps[2] + ps[3]);
    atomicAdd(&stats[COUT + o], ps2[0] + ps2[1] + ps2[2] + ps2[3]);
  }
}

// ---------------- Kernel D: normalize + ReLU in-place ----------------
__global__ __launch_bounds__(256) void bn_kernel(
    float* __restrict__ out, const float* __restrict__ stats,
    const float* __restrict__ gamma, const float* __restrict__ beta) {
  int i4 = (blockIdx.x * 256 + threadIdx.x) * 4;
  int o = (i4 >> 12) & (COUT - 1);
  const float inv_n = 1.f / (float)(BN_ * HW);
  float mean = stats[o] * inv_n;
  float var = stats[COUT + o] * inv_n - mean * mean;
  float sc = gamma[o] * rsqrtf(var + EPS);
  float sh = beta[o] - mean * sc;
  float4 v = *(float4*)(out + i4);
  v.x = fmaxf(fmaf(v.x, sc, sh), 0.f);
  v.y = fmaxf(fmaf(v.y, sc, sh), 0.f);
  v.z = fmaxf(fmaf(v.z, sc, sh), 0.f);
  v.w = fmaxf(fmaf(v.w, sc, sh), 0.f);
  *(float4*)(out + i4) = v;
}

extern "C" void kernel_launch(void* const* d_in, const int* in_sizes, int n_in,
                              void* d_out, int out_size, void* d_ws, size_t ws_size,
                              hipStream_t stream) {
  const float* x     = (const float*)d_in[0];
  const float* w_off = (const float*)d_in[1];
  const float* b_off = (const float*)d_in[2];
  const float* w     = (const float*)d_in[3];
  const float* bias  = (const float*)d_in[4];
  const float* gamma = (const float*)d_in[5];
  const float* beta  = (const float*)d_in[6];
  float* out = (float*)d_out;
  float* ws = (float*)d_ws;
  float* off_ws = ws + OFF_WS;
  unsigned short* wTb = (unsigned short*)(ws + WTB_WS);
  float* stats = ws + ST_WS;

  hipMemsetAsync(stats, 0, 2 * COUT * sizeof(float), stream);
  offset_kernel<<<dim3(HH, BN_, KK), 64, 0, stream>>>(x, w_off, b_off, off_ws);
  wtrans_kernel<<<72, 256, 0, stream>>>(w, wTb);
  gemm_kernel<<<512, 256, 0, stream>>>(x, wTb, off_ws, bias, out);
  stats_kernel<<<dim3(COUT, BN_), 256, 0, stream>>>(out, stats);
  bn_kernel<<<NTOT / 1024, 256, 0, stream>>>(out, stats, gamma, beta);
}

// Round 3
// 615.913 us; speedup vs baseline: 2.0018x; 1.0175x over previous
//
#include <hip/hip_runtime.h>
#include <math.h>

#define BN_ 8
#define CIN 256
#define COUT 256
#define HH 64
#define WW 64
#define HW 4096
#define KK 9
#define OC 18
#define EPS 1e-5f
#define NTOT (BN_ * COUT * HW)

// ws layout (float units):
//   off_ws: [B][18][HW]               = 589824 floats  (plane q=2kk -> dy, 2kk+1 -> dx)
//   wTb:    bf16 [72][256][40] shorts = 368640 floats
//   stats:  [2][COUT]                 = 512 floats
#define OFF_WS 0
#define WTB_WS 589824
#define ST_WS  (589824 + 368640)

typedef float f32x4 __attribute__((ext_vector_type(4)));
typedef short s16x8 __attribute__((ext_vector_type(8)));
typedef short s16x4 __attribute__((ext_vector_type(4)));

__device__ __forceinline__ unsigned short f2bf(float f) {
  unsigned int u = __float_as_uint(f);
  unsigned int r = (u + 0x7fffu + ((u >> 16) & 1u)) >> 16;  // RNE
  return (unsigned short)r;
}

// ---------------- Kernel A: offset conv, one pass over x ----------------
// grid (HH, B), block 256 = 4 waves. Wave wv owns outputs q = wv, wv+4, ...
// LDS: 3 halo rows x 64-ch chunk; rows padded to 72 (data at [4..67], zeros [3],[68])
// so float4 staging writes stay 16B-aligned and reads need no edge masking.
__global__ __launch_bounds__(256) void offset_kernel(
    const float* __restrict__ x, const float* __restrict__ w_off,
    const float* __restrict__ b_off, float* __restrict__ off_ws) {
  __shared__ float s_x[64][3][72];
  const int t = threadIdx.x;
  const int h = blockIdx.x;
  const int b = blockIdx.y;
  const int wv = t >> 6;
  const int px = t & 63;
  const float* xb = x + (size_t)b * CIN * HW;

  float acc[5];
#pragma unroll
  for (int m = 0; m < 5; ++m) {
    int q = wv + 4 * m;
    acc[m] = (q < OC) ? b_off[q] : 0.f;
  }

  for (int c0 = 0; c0 < CIN; c0 += 64) {
    __syncthreads();
    // stage 64 ch x 3 rows, 16 rows per iteration (16 threads/row, float4 each)
    const int rowlane = t >> 4;   // 0..15
    const int l16 = t & 15;
#pragma unroll
    for (int it = 0; it < 12; ++it) {
      int rid = it * 16 + rowlane;           // 0..191
      int c = rid / 3, r = rid - 3 * (rid / 3);
      int hh = h + r - 1;
      float4 v = make_float4(0.f, 0.f, 0.f, 0.f);
      if (hh >= 0 && hh < HH)
        v = *(const float4*)(xb + (size_t)(c0 + c) * HW + hh * WW + l16 * 4);
      *(float4*)&s_x[c][r][4 + l16 * 4] = v;
    }
    if (t < 192) { int c = t / 3, r = t - 3 * (t / 3); s_x[c][r][3] = 0.f; s_x[c][r][68] = 0.f; }
    __syncthreads();

    for (int c = 0; c < 64; ++c) {
      float v[9];
#pragma unroll
      for (int r = 0; r < 3; ++r)
#pragma unroll
        for (int j = 0; j < 3; ++j)
          v[r * 3 + j] = s_x[c][r][px + j + 3];
#pragma unroll
      for (int m = 0; m < 5; ++m) {
        int q = wv + 4 * m;
        if (q < OC) {
          const float* wp = w_off + (size_t)q * (CIN * 9) + (size_t)(c0 + c) * 9;
#pragma unroll
          for (int u = 0; u < 9; ++u) acc[m] = fmaf(v[u], wp[u], acc[m]);
        }
      }
    }
  }
#pragma unroll
  for (int m = 0; m < 5; ++m) {
    int q = wv + 4 * m;
    if (q < OC) off_ws[((size_t)b * OC + q) * HW + h * WW + px] = acc[m];
  }
}

// ---------------- Kernel W0: pack w -> bf16 fragment-friendly image ----------------
__global__ __launch_bounds__(256) void wtrans_kernel(
    const float* __restrict__ w, unsigned short* __restrict__ wTb) {
  const int kb = blockIdx.x;          // 0..71 : kk*8 + cstep
  const int kk = kb >> 3;
  const int c0 = (kb & 7) << 5;
  const int o = threadIdx.x;
  unsigned short* dst = wTb + ((size_t)kb * 256 + o) * 40;
  const float* src = w + ((size_t)o * CIN + c0) * 9 + kk;
#pragma unroll
  for (int kc = 0; kc < 32; ++kc) dst[kc] = f2bf(src[kc * 9]);
#pragma unroll
  for (int kc = 32; kc < 40; ++kc) dst[kc] = 0;
}

// ---------------- Kernel B: fused bilinear-gather MFMA GEMM ----------------
// grid 1024 (p-tiles of 32), block 256 = 4 waves. Block: out[b, 0..255, p0..p0+31].
// Wave wv -> o in [wv*64, wv*64+64). 4 blocks/CU (LDS 24KB) for gather latency hiding.
__global__ __launch_bounds__(256) void gemm_kernel(
    const float* __restrict__ x, const unsigned short* __restrict__ wTb,
    const float* __restrict__ off_ws, const float* __restrict__ bias,
    float* __restrict__ out) {
  __shared__ unsigned short s_a[256 * 40];  // [o][kc] bf16, 80B row stride
  __shared__ unsigned short s_b[32 * 40];   // [p][kc] bf16
  __shared__ int   s_ix[4][32];
  __shared__ float s_qw[4][32];
  const int t = threadIdx.x;
  const int lane = t & 63;
  const int wv = t >> 6;
  const int n0 = blockIdx.x * 32;
  const int b = n0 >> 12;
  const int p0 = n0 & (HW - 1);
  const float* xb = x + (size_t)b * CIN * HW;
  const int pg = t & 31;                // gather pixel
  const int cq = t >> 5;                // channel quad 0..7 (4 channels each)
  const int fr = lane & 15, fq = lane >> 4;

  f32x4 acc[4][2] = {};

  for (int kk = 0; kk < KK; ++kk) {
    __syncthreads();
    if (t < 32) {
      const float* ob = off_ws + ((size_t)(b * KK + kk) * 2) * HW + p0 + t;
      float dy = ob[0], dx = ob[HW];
      int p = p0 + t;
      int h = p >> 6, w_ = p & 63;
      float py = (float)(kk / 3 - 1 + h) + dy;
      float px = (float)(kk % 3 - 1 + w_) + dx;
      float y0f = floorf(py), x0f = floorf(px);
      float fy = py - y0f, fx = px - x0f;
      int y0 = (int)y0f, x0 = (int)x0f;
      int y1 = y0 + 1, x1 = x0 + 1;
      bool vy0 = (y0 >= 0) && (y0 < HH), vy1 = (y1 >= 0) && (y1 < HH);
      bool vx0 = (x0 >= 0) && (x0 < WW), vx1 = (x1 >= 0) && (x1 < WW);
      int cy0 = min(max(y0, 0), HH - 1), cy1 = min(max(y1, 0), HH - 1);
      int cx0 = min(max(x0, 0), WW - 1), cx1 = min(max(x1, 0), WW - 1);
      s_ix[0][t] = cy0 * WW + cx0;  s_qw[0][t] = (vy0 && vx0) ? (1.f - fy) * (1.f - fx) : 0.f;
      s_ix[1][t] = cy0 * WW + cx1;  s_qw[1][t] = (vy0 && vx1) ? (1.f - fy) * fx : 0.f;
      s_ix[2][t] = cy1 * WW + cx0;  s_qw[2][t] = (vy1 && vx0) ? fy * (1.f - fx) : 0.f;
      s_ix[3][t] = cy1 * WW + cx1;  s_qw[3][t] = (vy1 && vx1) ? fy * fx : 0.f;
    }

    for (int c0 = 0; c0 < CIN; c0 += 32) {
      __syncthreads();
      // ---- stage A: async copy 32 k-rows x 256 o (incl. pad) = 20480 B ----
      {
        const unsigned char* gb = (const unsigned char*)(wTb + ((size_t)(kk * 8 + (c0 >> 5)) * 256) * 40);
        unsigned char* lb = (unsigned char*)s_a;
#pragma unroll
        for (int i = 0; i < 5; ++i) {
          int chunk = (wv * 5 + i) * 1024;
          __builtin_amdgcn_global_load_lds(
              (const __attribute__((address_space(1))) unsigned char*)(gb + chunk + lane * 16),
              (__attribute__((address_space(3))) unsigned char*)(lb + chunk),
              16, 0, 0);
        }
      }
      // ---- stage B: bilinear gather -> bf16 (4 channels per thread) ----
      {
        int i0 = s_ix[0][pg], i1 = s_ix[1][pg], i2 = s_ix[2][pg], i3 = s_ix[3][pg];
        float q0 = s_qw[0][pg], q1 = s_qw[1][pg], q2 = s_qw[2][pg], q3 = s_qw[3][pg];
        const float* xp = xb + (size_t)(c0 + cq * 4) * HW;
        s16x4 v;
#pragma unroll
        for (int i = 0; i < 4; ++i) {
          const float* xc = xp + (size_t)i * HW;
          float val = q0 * xc[i0] + q1 * xc[i1] + q2 * xc[i2] + q3 * xc[i3];
          v[i] = (short)f2bf(val);
        }
        *(s16x4*)&s_b[pg * 40 + cq * 4] = v;
      }
      __syncthreads();
      // ---- fragments + MFMA ----
      {
        s16x8 af[4], bf[2];
#pragma unroll
        for (int j = 0; j < 2; ++j)
          bf[j] = *(const s16x8*)&s_b[(j * 16 + fr) * 40 + fq * 8];
#pragma unroll
        for (int i = 0; i < 4; ++i)
          af[i] = *(const s16x8*)&s_a[(wv * 64 + i * 16 + fr) * 40 + fq * 8];
#pragma unroll
        for (int i = 0; i < 4; ++i)
#pragma unroll
          for (int j = 0; j < 2; ++j)
            acc[i][j] = __builtin_amdgcn_mfma_f32_16x16x32_bf16(af[i], bf[j], acc[i][j], 0, 0, 0);
      }
    }
  }
  // ---- epilogue: + bias, store fp32 ----
#pragma unroll
  for (int i = 0; i < 4; ++i) {
#pragma unroll
    for (int rg = 0; rg < 4; ++rg) {
      int o = wv * 64 + i * 16 + fq * 4 + rg;
      float bv = bias[o];
      float* op = out + ((size_t)(b * COUT + o)) * HW + p0 + fr;
#pragma unroll
      for (int j = 0; j < 2; ++j)
        op[j * 16] = acc[i][j][rg] + bv;
    }
  }
}

// ---------------- Kernel C: per-channel sum/sumsq ----------------
__global__ __launch_bounds__(256) void stats_kernel(
    const float* __restrict__ out, float* __restrict__ stats) {
  const int o = blockIdx.x, b = blockIdx.y;
  const float* p = out + ((size_t)(b * COUT + o)) * HW;
  float s = 0.f, s2 = 0.f;
  for (int i = threadIdx.x * 4; i < HW; i += 1024) {
    float4 v = *(const float4*)(p + i);
    s += v.x + v.y + v.z + v.w;
    s2 += v.x * v.x + v.y * v.y + v.z * v.z + v.w * v.w;
  }
#pragma unroll
  for (int off = 32; off > 0; off >>= 1) {
    s += __shfl_down(s, off);
    s2 += __shfl_down(s2, off);
  }
  __shared__ float ps[4], ps2[4];
  int wid = threadIdx.x >> 6;
  if ((threadIdx.x & 63) == 0) { ps[wid] = s; ps2[wid] = s2; }
  __syncthreads();
  if (threadIdx.x == 0) {
    atomicAdd(&stats[o], ps[0] + ps[1] + ps[2] + ps[3]);
    atomicAdd(&stats[COUT + o], ps2[0] + ps2[1] + ps2[2] + ps2[3]);
  }
}

// ---------------- Kernel D: normalize + ReLU in-place ----------------
__global__ __launch_bounds__(256) void bn_kernel(
    float* __restrict__ out, const float* __restrict__ stats,
    const float* __restrict__ gamma, const float* __restrict__ beta) {
  int i4 = (blockIdx.x * 256 + threadIdx.x) * 4;
  int o = (i4 >> 12) & (COUT - 1);
  const float inv_n = 1.f / (float)(BN_ * HW);
  float mean = stats[o] * inv_n;
  float var = stats[COUT + o] * inv_n - mean * mean;
  float sc = gamma[o] * rsqrtf(var + EPS);
  float sh = beta[o] - mean * sc;
  float4 v = *(float4*)(out + i4);
  v.x = fmaxf(fmaf(v.x, sc, sh), 0.f);
  v.y = fmaxf(fmaf(v.y, sc, sh), 0.f);
  v.z = fmaxf(fmaf(v.z, sc, sh), 0.f);
  v.w = fmaxf(fmaf(v.w, sc, sh), 0.f);
  *(float4*)(out + i4) = v;
}

extern "C" void kernel_launch(void* const* d_in, const int* in_sizes, int n_in,
                              void* d_out, int out_size, void* d_ws, size_t ws_size,
                              hipStream_t stream) {
  const float* x     = (const float*)d_in[0];
  const float* w_off = (const float*)d_in[1];
  const float* b_off = (const float*)d_in[2];
  const float* w     = (const float*)d_in[3];
  const float* bias  = (const float*)d_in[4];
  const float* gamma = (const float*)d_in[5];
  const float* beta  = (const float*)d_in[6];
  float* out = (float*)d_out;
  float* ws = (float*)d_ws;
  float* off_ws = ws + OFF_WS;
  unsigned short* wTb = (unsigned short*)(ws + WTB_WS);
  float* stats = ws + ST_WS;

  hipMemsetAsync(stats, 0, 2 * COUT * sizeof(float), stream);
  offset_kernel<<<dim3(HH, BN_), 256, 0, stream>>>(x, w_off, b_off, off_ws);
  wtrans_kernel<<<72, 256, 0, stream>>>(w, wTb);
  gemm_kernel<<<1024, 256, 0, stream>>>(x, wTb, off_ws, bias, out);
  stats_kernel<<<dim3(COUT, BN_), 256, 0, stream>>>(out, stats);
  bn_kernel<<<NTOT / 1024, 256, 0, stream>>>(out, stats, gamma, beta);
}

// Round 4
// 554.530 us; speedup vs baseline: 2.2234x; 1.1107x over previous
//
#include <hip/hip_runtime.h>
#include <math.h>

#define BN_ 8
#define CIN 256
#define COUT 256
#define HH 64
#define WW 64
#define HW 4096
#define KK 9
#define OC 18
#define EPS 1e-5f
#define NTOT (BN_ * COUT * HW)

// ws layout (float units):
//   off_ws: [B][18][HW]                 = 589824 floats (plane 2kk=dy, 2kk+1=dx)
//   wTb:    bf16 [72][4][256][8] shorts = 589824 shorts = 294912 floats
//   stats:  [2][COUT]
#define OFF_WS 0
#define WTB_WS 589824
#define ST_WS  (589824 + 294912)

typedef float f32x4 __attribute__((ext_vector_type(4)));
typedef short s16x8 __attribute__((ext_vector_type(8)));

__device__ __forceinline__ unsigned short f2bf(float f) {
  unsigned int u = __float_as_uint(f);
  unsigned int r = (u + 0x7fffu + ((u >> 16) & 1u)) >> 16;  // RNE
  return (unsigned short)r;
}

// ---------------- Kernel A: offset conv, scalar weight loads ----------------
// grid (HH, B), block 256 = 4 waves. Wave wv owns q = wv, wv+4, ... (<18).
// Weights addressed via readfirstlane-uniform wave id -> s_load, SMEM-pipelined.
__global__ __launch_bounds__(256) void offset_kernel(
    const float* __restrict__ x, const float* __restrict__ w_off,
    const float* __restrict__ b_off, float* __restrict__ off_ws) {
  __shared__ float s_x[64][3][72];
  const int t = threadIdx.x;
  const int h = blockIdx.x;
  const int b = blockIdx.y;
  const int wvu = __builtin_amdgcn_readfirstlane(t >> 6);  // uniform wave id
  const int px = t & 63;
  const float* xb = x + (size_t)b * CIN * HW;

  float acc[5];
#pragma unroll
  for (int m = 0; m < 5; ++m) {
    int q = wvu + 4 * m;
    acc[m] = (q < OC) ? b_off[q] : 0.f;
  }

  for (int c0 = 0; c0 < CIN; c0 += 64) {
    __syncthreads();
    const int rowlane = t >> 4;
    const int l16 = t & 15;
#pragma unroll
    for (int it = 0; it < 12; ++it) {
      int rid = it * 16 + rowlane;           // 0..191
      int c = rid / 3, r = rid - 3 * (rid / 3);
      int hh = h + r - 1;
      float4 v = make_float4(0.f, 0.f, 0.f, 0.f);
      if (hh >= 0 && hh < HH)
        v = *(const float4*)(xb + (size_t)(c0 + c) * HW + hh * WW + l16 * 4);
      *(float4*)&s_x[c][r][4 + l16 * 4] = v;
    }
    if (t < 192) { int c = t / 3, r = t - 3 * (t / 3); s_x[c][r][3] = 0.f; s_x[c][r][68] = 0.f; }
    __syncthreads();

    for (int c = 0; c < 64; ++c) {
      float v[9];
#pragma unroll
      for (int r = 0; r < 3; ++r)
#pragma unroll
        for (int j = 0; j < 3; ++j)
          v[r * 3 + j] = s_x[c][r][px + j + 3];
#pragma unroll
      for (int m = 0; m < 5; ++m) {
        int q = wvu + 4 * m;
        if (q < OC) {
          const float* wp = w_off + ((size_t)q * CIN + (c0 + c)) * 9;  // uniform -> s_load
#pragma unroll
          for (int u = 0; u < 9; ++u) acc[m] = fmaf(v[u], wp[u], acc[m]);
        }
      }
    }
  }
#pragma unroll
  for (int m = 0; m < 5; ++m) {
    int q = wvu + 4 * m;
    if (q < OC) off_ws[((size_t)b * OC + q) * HW + h * WW + px] = acc[m];
  }
}

// ---------------- Kernel W0: pack w -> bf16 k-major image ----------------
// wTb[kb][g][o][j] = bf16(w[o][(kb%8)*32 + g*8 + j][kb/8]),  kb=kk*8+cstep
__global__ __launch_bounds__(256) void wtrans_kernel(
    const float* __restrict__ w, unsigned short* __restrict__ wTb) {
  const int kb = blockIdx.x;          // 0..71
  const int kk = kb >> 3;
  const int c0 = (kb & 7) << 5;
  const int o = threadIdx.x;
#pragma unroll
  for (int g = 0; g < 4; ++g)
#pragma unroll
    for (int j = 0; j < 8; ++j) {
      int c = c0 + g * 8 + j;
      wTb[(((size_t)kb * 4 + g) * 256 + o) * 8 + j] =
          f2bf(w[((size_t)o * CIN + c) * 9 + kk]);
    }
}

// ---------------- Kernel B: fused bilinear-gather MFMA GEMM, pipelined ----------------
// grid 512: b = bx&7 (XCD affinity), h = bx>>3. Block = 256 thr = 4 waves.
// Tile: out[b, 0..255, h*64 .. h*64+63]. 72 k-iters (9 kk x 8 c-chunks of 32).
// LDS double-buffered: s_a[2] 16KB (A k-major), s_b[2] 4KB, idx/qw per kk-parity.
#define SA_SZ 8192   // shorts per A buffer: 4*256*8
#define SB_SZ 2048   // shorts per B buffer: 4*64*8

__global__ __launch_bounds__(256) void gemm_kernel(
    const float* __restrict__ x, const unsigned short* __restrict__ wTb,
    const float* __restrict__ off_ws, const float* __restrict__ bias,
    float* __restrict__ out) {
  __shared__ unsigned short s_a[2][SA_SZ];
  __shared__ unsigned short s_b[2][SB_SZ];
  __shared__ int   s_ix[2][4][64];   // byte offsets into a channel plane
  __shared__ float s_qw[2][4][64];
  const int t = threadIdx.x;
  const int lane = t & 63;
  const int wv = t >> 6;
  const int b = blockIdx.x & 7;
  const int h = blockIdx.x >> 3;
  const int p0 = h * 64;
  const float* xb = x + (size_t)b * CIN * HW;
  const int pg = t & 63;               // gather pixel (= frag n lane too)
  const int cq = t >> 6;               // channel-octet 0..3
  const int fr = lane & 15, fq = lane >> 4;

  // ---- idx/qw computation for one kk ----
  auto comp_idx = [&](int kk, int buf) {
    const float* ob = off_ws + ((size_t)(b * KK + kk) * 2) * HW + p0 + t;
    float dy = ob[0], dx = ob[HW];
    int w_ = t;
    float py = (float)(kk / 3 - 1 + h) + dy;
    float px = (float)(kk % 3 - 1 + w_) + dx;
    float y0f = floorf(py), x0f = floorf(px);
    float fy = py - y0f, fx = px - x0f;
    int y0 = (int)y0f, x0 = (int)x0f;
    int y1 = y0 + 1, x1 = x0 + 1;
    bool vy0 = (y0 >= 0) && (y0 < HH), vy1 = (y1 >= 0) && (y1 < HH);
    bool vx0 = (x0 >= 0) && (x0 < WW), vx1 = (x1 >= 0) && (x1 < WW);
    int cy0 = min(max(y0, 0), HH - 1), cy1 = min(max(y1, 0), HH - 1);
    int cx0 = min(max(x0, 0), WW - 1), cx1 = min(max(x1, 0), WW - 1);
    s_ix[buf][0][t] = (cy0 * WW + cx0) * 4;  s_qw[buf][0][t] = (vy0 && vx0) ? (1.f - fy) * (1.f - fx) : 0.f;
    s_ix[buf][1][t] = (cy0 * WW + cx1) * 4;  s_qw[buf][1][t] = (vy0 && vx1) ? (1.f - fy) * fx : 0.f;
    s_ix[buf][2][t] = (cy1 * WW + cx0) * 4;  s_qw[buf][2][t] = (vy1 && vx0) ? fy * (1.f - fx) : 0.f;
    s_ix[buf][3][t] = (cy1 * WW + cx1) * 4;  s_qw[buf][3][t] = (vy1 && vx1) ? fy * fx : 0.f;
  };

  auto stage_a = [&](int iter, int buf) {
    const unsigned char* gb = (const unsigned char*)(wTb + (size_t)iter * SA_SZ);
    unsigned char* lb = (unsigned char*)s_a[buf];
#pragma unroll
    for (int i = 0; i < 4; ++i) {
      int chunk = (wv * 4 + i) * 1024;
      __builtin_amdgcn_global_load_lds(
          (const __attribute__((address_space(1))) unsigned char*)(gb + chunk + lane * 16),
          (__attribute__((address_space(3))) unsigned char*)(lb + chunk),
          16, 0, 0);
    }
  };

  f32x4 acc[4][4] = {};
  int j0, j1, j2, j3;         // corner byte offsets (this thread's pixel)
  float q0, q1, q2, q3;       // corner weights
  float r0[8], r1[8], r2[8], r3[8];

  auto load_idx = [&](int buf) {
    j0 = s_ix[buf][0][pg]; j1 = s_ix[buf][1][pg];
    j2 = s_ix[buf][2][pg]; j3 = s_ix[buf][3][pg];
    q0 = s_qw[buf][0][pg]; q1 = s_qw[buf][1][pg];
    q2 = s_qw[buf][2][pg]; q3 = s_qw[buf][3][pg];
  };

  auto gather = [&](int c0n) {
    const unsigned char* bp = (const unsigned char*)(xb + (size_t)(c0n + cq * 8) * HW);
#pragma unroll
    for (int i = 0; i < 8; ++i) {
      r0[i] = *(const float*)(bp + j0);
      r1[i] = *(const float*)(bp + j1);
      r2[i] = *(const float*)(bp + j2);
      r3[i] = *(const float*)(bp + j3);
      bp += HW * 4;
    }
  };

  auto combine_write = [&](int buf) {
    s16x8 v;
#pragma unroll
    for (int i = 0; i < 8; ++i) {
      float val = q0 * r0[i] + q1 * r1[i] + q2 * r2[i] + q3 * r3[i];
      v[i] = (short)f2bf(val);
    }
    *(s16x8*)&s_b[buf][(cq * 64 + pg) * 8] = v;
  };

  // ---- prologue: iter 0 ----
  if (t < 64) comp_idx(0, 0);
  stage_a(0, 0);
  __syncthreads();
  load_idx(0);
  gather(0);
  combine_write(0);
  __syncthreads();

  for (int iter = 0; iter < 72; ++iter) {
    const int cur = iter & 1;
    const int kk = iter >> 3;
    // compute idx for kk+1 one kk ahead (consumed 7 iters later; barriers cover)
    if ((iter & 7) == 0 && kk < 8 && t < 64) comp_idx(kk + 1, (kk + 1) & 1);

    // frag reads for current iter
    s16x8 af[4], bf[4];
#pragma unroll
    for (int i = 0; i < 4; ++i)
      af[i] = *(const s16x8*)&s_a[cur][((fq * 256) + wv * 64 + i * 16 + fr) * 8];
#pragma unroll
    for (int j = 0; j < 4; ++j)
      bf[j] = *(const s16x8*)&s_b[cur][((fq * 64) + j * 16 + fr) * 8];

    const int nxt = iter + 1;
    if (nxt < 72) {
      stage_a(nxt, cur ^ 1);
      const int kkn = nxt >> 3, c0n = (nxt & 7) << 5;
      if ((nxt & 7) == 0) load_idx(kkn & 1);
      gather(c0n);
    }

#pragma unroll
    for (int i = 0; i < 4; ++i)
#pragma unroll
      for (int j = 0; j < 4; ++j)
        acc[i][j] = __builtin_amdgcn_mfma_f32_16x16x32_bf16(af[i], bf[j], acc[i][j], 0, 0, 0);

    if (nxt < 72) combine_write(cur ^ 1);
    __syncthreads();
  }

  // ---- epilogue: + bias, store fp32 ----
#pragma unroll
  for (int i = 0; i < 4; ++i) {
#pragma unroll
    for (int rg = 0; rg < 4; ++rg) {
      int o = wv * 64 + i * 16 + fq * 4 + rg;
      float bv = bias[o];
      float* op = out + ((size_t)(b * COUT + o)) * HW + p0 + fr;
#pragma unroll
      for (int j = 0; j < 4; ++j)
        op[j * 16] = acc[i][j][rg] + bv;
    }
  }
}

// ---------------- Kernel C: per-channel sum/sumsq ----------------
__global__ __launch_bounds__(256) void stats_kernel(
    const float* __restrict__ out, float* __restrict__ stats) {
  const int o = blockIdx.x, b = blockIdx.y;
  const float* p = out + ((size_t)(b * COUT + o)) * HW;
  float s = 0.f, s2 = 0.f;
  for (int i = threadIdx.x * 4; i < HW; i += 1024) {
    float4 v = *(const float4*)(p + i);
    s += v.x + v.y + v.z + v.w;
    s2 += v.x * v.x + v.y * v.y + v.z * v.z + v.w * v.w;
  }
#pragma unroll
  for (int off = 32; off > 0; off >>= 1) {
    s += __shfl_down(s, off);
    s2 += __shfl_down(s2, off);
  }
  __shared__ float ps[4], ps2[4];
  int wid = threadIdx.x >> 6;
  if ((threadIdx.x & 63) == 0) { ps[wid] = s; ps2[wid] = s2; }
  __syncthreads();
  if (threadIdx.x == 0) {
    atomicAdd(&stats[o], ps[0] + ps[1] + ps[2] + ps[3]);
    atomicAdd(&stats[COUT + o], ps2[0] + ps2[1] + ps2[2] + ps2[3]);
  }
}

// ---------------- Kernel D: normalize + ReLU in-place ----------------
__global__ __launch_bounds__(256) void bn_kernel(
    float* __restrict__ out, const float* __restrict__ stats,
    const float* __restrict__ gamma, const float* __restrict__ beta) {
  int i4 = (blockIdx.x * 256 + threadIdx.x) * 4;
  int o = (i4 >> 12) & (COUT - 1);
  const float inv_n = 1.f / (float)(BN_ * HW);
  float mean = stats[o] * inv_n;
  float var = stats[COUT + o] * inv_n - mean * mean;
  float sc = gamma[o] * rsqrtf(var + EPS);
  float sh = beta[o] - mean * sc;
  float4 v = *(float4*)(out + i4);
  v.x = fmaxf(fmaf(v.x, sc, sh), 0.f);
  v.y = fmaxf(fmaf(v.y, sc, sh), 0.f);
  v.z = fmaxf(fmaf(v.z, sc, sh), 0.f);
  v.w = fmaxf(fmaf(v.w, sc, sh), 0.f);
  *(float4*)(out + i4) = v;
}

extern "C" void kernel_launch(void* const* d_in, const int* in_sizes, int n_in,
                              void* d_out, int out_size, void* d_ws, size_t ws_size,
                              hipStream_t stream) {
  const float* x     = (const float*)d_in[0];
  const float* w_off = (const float*)d_in[1];
  const float* b_off = (const float*)d_in[2];
  const float* w     = (const float*)d_in[3];
  const float* bias  = (const float*)d_in[4];
  const float* gamma = (const float*)d_in[5];
  const float* beta  = (const float*)d_in[6];
  float* out = (float*)d_out;
  float* ws = (float*)d_ws;
  float* off_ws = ws + OFF_WS;
  unsigned short* wTb = (unsigned short*)(ws + WTB_WS);
  float* stats = ws + ST_WS;

  hipMemsetAsync(stats, 0, 2 * COUT * sizeof(float), stream);
  offset_kernel<<<dim3(HH, BN_), 256, 0, stream>>>(x, w_off, b_off, off_ws);
  wtrans_kernel<<<72, 256, 0, stream>>>(w, wTb);
  gemm_kernel<<<512, 256, 0, stream>>>(x, wTb, off_ws, bias, out);
  stats_kernel<<<dim3(COUT, BN_), 256, 0, stream>>>(out, stats);
  bn_kernel<<<NTOT / 1024, 256, 0, stream>>>(out, stats, gamma, beta);
}

// Round 5
// 388.822 us; speedup vs baseline: 3.1709x; 1.4262x over previous
//
#include <hip/hip_runtime.h>
#include <math.h>

#define BN_ 8
#define CIN 256
#define COUT 256
#define HH 64
#define WW 64
#define HW 4096
#define KK 9
#define OC 18
#define EPS 1e-5f
#define NTOT (BN_ * COUT * HW)

// ws layout (float units):
//   off_ws: [B][18][HW]                 = 589824 floats (plane 2kk=dy, 2kk+1=dx)
//   wTb:    bf16 [72][4][256][8] shorts = 294912 floats (main GEMM A image)
//   wob:    bf16 [72][4][32][8] shorts  = 36864 floats  (offset-conv A image, M=32 pad)
//   stats:  [2][COUT]
#define OFF_WS 0
#define WTB_WS 589824
#define WOB_WS 884736
#define ST_WS  921600

typedef float f32x4 __attribute__((ext_vector_type(4)));
typedef short s16x8 __attribute__((ext_vector_type(8)));

__device__ __forceinline__ unsigned short f2bf(float f) {
  unsigned int u = __float_as_uint(f);
  unsigned int r = (u + 0x7fffu + ((u >> 16) & 1u)) >> 16;  // RNE
  return (unsigned short)r;
}

// ---------------- Kernel W1: pack w_off -> bf16 fragment image (M=32 pad) ----------------
// wob[ki][g][m][j] = bf16(w_off[m][(ki&7)*32 + g*8 + j][ki>>3]), m<18; else 0.
__global__ __launch_bounds__(256) void wob_kernel(
    const float* __restrict__ w_off, unsigned short* __restrict__ wob) {
  const int ki = blockIdx.x;          // 0..71
  const int kk = ki >> 3;
  const int cc0 = (ki & 7) << 5;
#pragma unroll
  for (int r = 0; r < 4; ++r) {
    int e = r * 256 + threadIdx.x;    // 0..1023 = g*256 + m*8 + j
    int g = e >> 8, m = (e >> 3) & 31, j = e & 7;
    int c = cc0 + g * 8 + j;
    unsigned short v = 0;
    if (m < OC) v = f2bf(w_off[((size_t)m * CIN + c) * 9 + kk]);
    wob[(size_t)ki * 1024 + e] = v;
  }
}

// ---------------- Kernel A: offset conv as MFMA GEMM, K-split across waves ----------------
// grid 512: b = bx&7, h = bx>>3. Block 256 = 4 waves; wave wv owns k-iters wv*18..+17.
// No barriers in main loop: each wave stages its own B-tile in a private LDS region.
// A frags read straight global->VGPR (wob is L2-resident). Epilogue: LDS reduction.
__global__ __launch_bounds__(256) void offset_kernel(
    const float* __restrict__ x, const unsigned short* __restrict__ wob,
    const float* __restrict__ b_off, float* __restrict__ off_ws) {
  __shared__ __align__(16) char smem[32768];   // 4x4KB wave B-tiles, reused as 32KB reduction
  const int t = threadIdx.x;
  const int lane = t & 63;
  const int wv = t >> 6;
  const int b = blockIdx.x & 7;
  const int h = blockIdx.x >> 3;
  const float* xb = x + (size_t)b * CIN * HW;
  const int fr = lane & 15, fq = lane >> 4;
  unsigned short* sb = (unsigned short*)smem + wv * 2048;
  float* red = (float*)smem;

  f32x4 acc[2][4] = {};

  for (int s = 0; s < 18; ++s) {
    const int ki = wv * 18 + s;
    const int kk = ki >> 3, cc0 = (ki & 7) << 5;
    const int ky = kk / 3 - 1, kx = kk % 3 - 1;
    const int y = h + ky;
    const bool yok = (y >= 0) && (y < HH);
    const int xcol = lane + kx;
    const bool ok = yok && (xcol >= 0) && (xcol < WW);

    // A frags: global -> VGPR (issued first; vmcnt drains them with the gathers)
    s16x8 af[2];
    const unsigned short* ap = wob + (size_t)ki * 1024;
#pragma unroll
    for (int i = 0; i < 2; ++i)
      af[i] = *(const s16x8*)&ap[(fq * 32 + i * 16 + fr) * 8];

    // B-tile: im2col loads (coalesced across lanes), pack bf16, private-LDS write
    const float* bp = xb + (size_t)cc0 * HW + y * WW + xcol;
#pragma unroll
    for (int g = 0; g < 4; ++g) {
      s16x8 v;
#pragma unroll
      for (int j = 0; j < 8; ++j) {
        float val = ok ? bp[(size_t)(g * 8 + j) * HW] : 0.f;
        v[j] = (short)f2bf(val);
      }
      *(s16x8*)&sb[(g * 64 + lane) * 8] = v;
    }
    __builtin_amdgcn_s_waitcnt(0);   // wave-local: ds_writes + A loads complete

    s16x8 bf[4];
#pragma unroll
    for (int jn = 0; jn < 4; ++jn)
      bf[jn] = *(const s16x8*)&sb[(fq * 64 + jn * 16 + fr) * 8];
#pragma unroll
    for (int i = 0; i < 2; ++i)
#pragma unroll
      for (int jn = 0; jn < 4; ++jn)
        acc[i][jn] = __builtin_amdgcn_mfma_f32_16x16x32_bf16(af[i], bf[jn], acc[i][jn], 0, 0, 0);
  }

  // ---- cross-wave K reduction via LDS ----
  __syncthreads();
#pragma unroll
  for (int i = 0; i < 2; ++i)
#pragma unroll
    for (int jn = 0; jn < 4; ++jn)
#pragma unroll
      for (int rg = 0; rg < 4; ++rg)
        red[wv * 2048 + (i * 16 + fq * 4 + rg) * 64 + jn * 16 + fr] = acc[i][jn][rg];
  __syncthreads();

  const int m = t >> 3;              // 0..31
  const int pq = (t & 7) * 8;
  float4 v0 = make_float4(0.f, 0.f, 0.f, 0.f), v1 = v0;
#pragma unroll
  for (int w = 0; w < 4; ++w) {
    float4 a = *(float4*)&red[w * 2048 + m * 64 + pq];
    float4 c = *(float4*)&red[w * 2048 + m * 64 + pq + 4];
    v0.x += a.x; v0.y += a.y; v0.z += a.z; v0.w += a.w;
    v1.x += c.x; v1.y += c.y; v1.z += c.z; v1.w += c.w;
  }
  if (m < OC) {
    float bo = b_off[m];
    v0.x += bo; v0.y += bo; v0.z += bo; v0.w += bo;
    v1.x += bo; v1.y += bo; v1.z += bo; v1.w += bo;
    float* op = off_ws + ((size_t)b * OC + m) * HW + h * WW + pq;
    *(float4*)op = v0;
    *(float4*)(op + 4) = v1;
  }
}

// ---------------- Kernel W0: pack w -> bf16 k-major image ----------------
__global__ __launch_bounds__(256) void wtrans_kernel(
    const float* __restrict__ w, unsigned short* __restrict__ wTb) {
  const int kb = blockIdx.x;          // 0..71
  const int kk = kb >> 3;
  const int c0 = (kb & 7) << 5;
  const int o = threadIdx.x;
#pragma unroll
  for (int g = 0; g < 4; ++g)
#pragma unroll
    for (int j = 0; j < 8; ++j) {
      int c = c0 + g * 8 + j;
      wTb[(((size_t)kb * 4 + g) * 256 + o) * 8 + j] =
          f2bf(w[((size_t)o * CIN + c) * 9 + kk]);
    }
}

// ---------------- Kernel B: fused bilinear-gather MFMA GEMM, pipelined ----------------
#define SA_SZ 8192   // shorts per A buffer: 4*256*8
#define SB_SZ 2048   // shorts per B buffer: 4*64*8

__global__ __launch_bounds__(256) void gemm_kernel(
    const float* __restrict__ x, const unsigned short* __restrict__ wTb,
    const float* __restrict__ off_ws, const float* __restrict__ bias,
    float* __restrict__ out) {
  __shared__ unsigned short s_a[2][SA_SZ];
  __shared__ unsigned short s_b[2][SB_SZ];
  __shared__ int   s_ix[2][4][64];
  __shared__ float s_qw[2][4][64];
  const int t = threadIdx.x;
  const int lane = t & 63;
  const int wv = t >> 6;
  const int b = blockIdx.x & 7;
  const int h = blockIdx.x >> 3;
  const int p0 = h * 64;
  const float* xb = x + (size_t)b * CIN * HW;
  const int pg = t & 63;
  const int cq = t >> 6;
  const int fr = lane & 15, fq = lane >> 4;

  auto comp_idx = [&](int kk, int buf) {
    const float* ob = off_ws + ((size_t)(b * KK + kk) * 2) * HW + p0 + t;
    float dy = ob[0], dx = ob[HW];
    int w_ = t;
    float py = (float)(kk / 3 - 1 + h) + dy;
    float px = (float)(kk % 3 - 1 + w_) + dx;
    float y0f = floorf(py), x0f = floorf(px);
    float fy = py - y0f, fx = px - x0f;
    int y0 = (int)y0f, x0 = (int)x0f;
    int y1 = y0 + 1, x1 = x0 + 1;
    bool vy0 = (y0 >= 0) && (y0 < HH), vy1 = (y1 >= 0) && (y1 < HH);
    bool vx0 = (x0 >= 0) && (x0 < WW), vx1 = (x1 >= 0) && (x1 < WW);
    int cy0 = min(max(y0, 0), HH - 1), cy1 = min(max(y1, 0), HH - 1);
    int cx0 = min(max(x0, 0), WW - 1), cx1 = min(max(x1, 0), WW - 1);
    s_ix[buf][0][t] = (cy0 * WW + cx0) * 4;  s_qw[buf][0][t] = (vy0 && vx0) ? (1.f - fy) * (1.f - fx) : 0.f;
    s_ix[buf][1][t] = (cy0 * WW + cx1) * 4;  s_qw[buf][1][t] = (vy0 && vx1) ? (1.f - fy) * fx : 0.f;
    s_ix[buf][2][t] = (cy1 * WW + cx0) * 4;  s_qw[buf][2][t] = (vy1 && vx0) ? fy * (1.f - fx) : 0.f;
    s_ix[buf][3][t] = (cy1 * WW + cx1) * 4;  s_qw[buf][3][t] = (vy1 && vx1) ? fy * fx : 0.f;
  };

  auto stage_a = [&](int iter, int buf) {
    const unsigned char* gb = (const unsigned char*)(wTb + (size_t)iter * SA_SZ);
    unsigned char* lb = (unsigned char*)s_a[buf];
#pragma unroll
    for (int i = 0; i < 4; ++i) {
      int chunk = (wv * 4 + i) * 1024;
      __builtin_amdgcn_global_load_lds(
          (const __attribute__((address_space(1))) unsigned char*)(gb + chunk + lane * 16),
          (__attribute__((address_space(3))) unsigned char*)(lb + chunk),
          16, 0, 0);
    }
  };

  f32x4 acc[4][4] = {};
  int j0, j1, j2, j3;
  float q0, q1, q2, q3;
  float r0[8], r1[8], r2[8], r3[8];

  auto load_idx = [&](int buf) {
    j0 = s_ix[buf][0][pg]; j1 = s_ix[buf][1][pg];
    j2 = s_ix[buf][2][pg]; j3 = s_ix[buf][3][pg];
    q0 = s_qw[buf][0][pg]; q1 = s_qw[buf][1][pg];
    q2 = s_qw[buf][2][pg]; q3 = s_qw[buf][3][pg];
  };

  auto gather = [&](int c0n) {
    const unsigned char* bp = (const unsigned char*)(xb + (size_t)(c0n + cq * 8) * HW);
#pragma unroll
    for (int i = 0; i < 8; ++i) {
      r0[i] = *(const float*)(bp + j0);
      r1[i] = *(const float*)(bp + j1);
      r2[i] = *(const float*)(bp + j2);
      r3[i] = *(const float*)(bp + j3);
      bp += HW * 4;
    }
  };

  auto combine_write = [&](int buf) {
    s16x8 v;
#pragma unroll
    for (int i = 0; i < 8; ++i) {
      float val = q0 * r0[i] + q1 * r1[i] + q2 * r2[i] + q3 * r3[i];
      v[i] = (short)f2bf(val);
    }
    *(s16x8*)&s_b[buf][(cq * 64 + pg) * 8] = v;
  };

  if (t < 64) comp_idx(0, 0);
  stage_a(0, 0);
  __syncthreads();
  load_idx(0);
  gather(0);
  combine_write(0);
  __syncthreads();

  for (int iter = 0; iter < 72; ++iter) {
    const int cur = iter & 1;
    const int kk = iter >> 3;
    if ((iter & 7) == 0 && kk < 8 && t < 64) comp_idx(kk + 1, (kk + 1) & 1);

    s16x8 af[4], bf[4];
#pragma unroll
    for (int i = 0; i < 4; ++i)
      af[i] = *(const s16x8*)&s_a[cur][((fq * 256) + wv * 64 + i * 16 + fr) * 8];
#pragma unroll
    for (int j = 0; j < 4; ++j)
      bf[j] = *(const s16x8*)&s_b[cur][((fq * 64) + j * 16 + fr) * 8];

    const int nxt = iter + 1;
    if (nxt < 72) {
      stage_a(nxt, cur ^ 1);
      const int kkn = nxt >> 3, c0n = (nxt & 7) << 5;
      if ((nxt & 7) == 0) load_idx(kkn & 1);
      gather(c0n);
    }

#pragma unroll
    for (int i = 0; i < 4; ++i)
#pragma unroll
      for (int j = 0; j < 4; ++j)
        acc[i][j] = __builtin_amdgcn_mfma_f32_16x16x32_bf16(af[i], bf[j], acc[i][j], 0, 0, 0);

    if (nxt < 72) combine_write(cur ^ 1);
    __syncthreads();
  }

#pragma unroll
  for (int i = 0; i < 4; ++i) {
#pragma unroll
    for (int rg = 0; rg < 4; ++rg) {
      int o = wv * 64 + i * 16 + fq * 4 + rg;
      float bv = bias[o];
      float* op = out + ((size_t)(b * COUT + o)) * HW + p0 + fr;
#pragma unroll
      for (int j = 0; j < 4; ++j)
        op[j * 16] = acc[i][j][rg] + bv;
    }
  }
}

// ---------------- Kernel C: per-channel sum/sumsq ----------------
__global__ __launch_bounds__(256) void stats_kernel(
    const float* __restrict__ out, float* __restrict__ stats) {
  const int o = blockIdx.x, b = blockIdx.y;
  const float* p = out + ((size_t)(b * COUT + o)) * HW;
  float s = 0.f, s2 = 0.f;
  for (int i = threadIdx.x * 4; i < HW; i += 1024) {
    float4 v = *(const float4*)(p + i);
    s += v.x + v.y + v.z + v.w;
    s2 += v.x * v.x + v.y * v.y + v.z * v.z + v.w * v.w;
  }
#pragma unroll
  for (int off = 32; off > 0; off >>= 1) {
    s += __shfl_down(s, off);
    s2 += __shfl_down(s2, off);
  }
  __shared__ float ps[4], ps2[4];
  int wid = threadIdx.x >> 6;
  if ((threadIdx.x & 63) == 0) { ps[wid] = s; ps2[wid] = s2; }
  __syncthreads();
  if (threadIdx.x == 0) {
    atomicAdd(&stats[o], ps[0] + ps[1] + ps[2] + ps[3]);
    atomicAdd(&stats[COUT + o], ps2[0] + ps2[1] + ps2[2] + ps2[3]);
  }
}

// ---------------- Kernel D: normalize + ReLU in-place ----------------
__global__ __launch_bounds__(256) void bn_kernel(
    float* __restrict__ out, const float* __restrict__ stats,
    const float* __restrict__ gamma, const float* __restrict__ beta) {
  int i4 = (blockIdx.x * 256 + threadIdx.x) * 4;
  int o = (i4 >> 12) & (COUT - 1);
  const float inv_n = 1.f / (float)(BN_ * HW);
  float mean = stats[o] * inv_n;
  float var = stats[COUT + o] * inv_n - mean * mean;
  float sc = gamma[o] * rsqrtf(var + EPS);
  float sh = beta[o] - mean * sc;
  float4 v = *(float4*)(out + i4);
  v.x = fmaxf(fmaf(v.x, sc, sh), 0.f);
  v.y = fmaxf(fmaf(v.y, sc, sh), 0.f);
  v.z = fmaxf(fmaf(v.z, sc, sh), 0.f);
  v.w = fmaxf(fmaf(v.w, sc, sh), 0.f);
  *(float4*)(out + i4) = v;
}

extern "C" void kernel_launch(void* const* d_in, const int* in_sizes, int n_in,
                              void* d_out, int out_size, void* d_ws, size_t ws_size,
                              hipStream_t stream) {
  const float* x     = (const float*)d_in[0];
  const float* w_off = (const float*)d_in[1];
  const float* b_off = (const float*)d_in[2];
  const float* w     = (const float*)d_in[3];
  const float* bias  = (const float*)d_in[4];
  const float* gamma = (const float*)d_in[5];
  const float* beta  = (const float*)d_in[6];
  float* out = (float*)d_out;
  float* ws = (float*)d_ws;
  float* off_ws = ws + OFF_WS;
  unsigned short* wTb = (unsigned short*)(ws + WTB_WS);
  unsigned short* wob = (unsigned short*)(ws + WOB_WS);
  float* stats = ws + ST_WS;

  hipMemsetAsync(stats, 0, 2 * COUT * sizeof(float), stream);
  wob_kernel<<<72, 256, 0, stream>>>(w_off, wob);
  wtrans_kernel<<<72, 256, 0, stream>>>(w, wTb);
  offset_kernel<<<512, 256, 0, stream>>>(x, wob, b_off, off_ws);
  gemm_kernel<<<512, 256, 0, stream>>>(x, wTb, off_ws, bias, out);
  stats_kernel<<<dim3(COUT, BN_), 256, 0, stream>>>(out, stats);
  bn_kernel<<<NTOT / 1024, 256, 0, stream>>>(out, stats, gamma, beta);
}

// Round 6
// 372.794 us; speedup vs baseline: 3.3072x; 1.0430x over previous
//
#include <hip/hip_runtime.h>
#include <math.h>

#define BN_ 8
#define CIN 256
#define COUT 256
#define HH 64
#define WW 64
#define HW 4096
#define KK 9
#define OC 18
#define EPS 1e-5f
#define NTOT (BN_ * COUT * HW)

// ws layout (float units):
//   off_ws: [B][18][HW]                 = 589824 floats (plane 2kk=dy, 2kk+1=dx)
//   wTb:    bf16 [72][4][256][8] shorts = 294912 floats (main GEMM A image)
//   wob:    bf16 [72][4][32][8] shorts  = 36864 floats  (offset-conv A image, M=32 pad)
//   stats:  [2][COUT]
#define OFF_WS 0
#define WTB_WS 589824
#define WOB_WS 884736
#define ST_WS  921600

typedef float f32x4 __attribute__((ext_vector_type(4)));
typedef float f32x2 __attribute__((ext_vector_type(2)));
typedef short s16x8 __attribute__((ext_vector_type(8)));

__device__ __forceinline__ unsigned short f2bf(float f) {
  unsigned int u = __float_as_uint(f);
  unsigned int r = (u + 0x7fffu + ((u >> 16) & 1u)) >> 16;  // RNE
  return (unsigned short)r;
}

// ---------------- Kernel W1: pack w_off -> bf16 fragment image (M=32 pad) ----------------
__global__ __launch_bounds__(256) void wob_kernel(
    const float* __restrict__ w_off, unsigned short* __restrict__ wob) {
  const int ki = blockIdx.x;          // 0..71
  const int kk = ki >> 3;
  const int cc0 = (ki & 7) << 5;
#pragma unroll
  for (int r = 0; r < 4; ++r) {
    int e = r * 256 + threadIdx.x;    // 0..1023 = g*256 + m*8 + j
    int g = e >> 8, m = (e >> 3) & 31, j = e & 7;
    int c = cc0 + g * 8 + j;
    unsigned short v = 0;
    if (m < OC) v = f2bf(w_off[((size_t)m * CIN + c) * 9 + kk]);
    wob[(size_t)ki * 1024 + e] = v;
  }
}

// ---------------- Kernel A: offset conv as MFMA GEMM, K-split across waves ----------------
__global__ __launch_bounds__(256) void offset_kernel(
    const float* __restrict__ x, const unsigned short* __restrict__ wob,
    const float* __restrict__ b_off, float* __restrict__ off_ws) {
  __shared__ __align__(16) char smem[32768];
  const int t = threadIdx.x;
  const int lane = t & 63;
  const int wv = t >> 6;
  const int b = blockIdx.x & 7;
  const int h = blockIdx.x >> 3;
  const float* xb = x + (size_t)b * CIN * HW;
  const int fr = lane & 15, fq = lane >> 4;
  unsigned short* sb = (unsigned short*)smem + wv * 2048;
  float* red = (float*)smem;

  f32x4 acc[2][4] = {};

  for (int s = 0; s < 18; ++s) {
    const int ki = wv * 18 + s;
    const int kk = ki >> 3, cc0 = (ki & 7) << 5;
    const int ky = kk / 3 - 1, kx = kk % 3 - 1;
    const int y = h + ky;
    const bool yok = (y >= 0) && (y < HH);
    const int xcol = lane + kx;
    const bool ok = yok && (xcol >= 0) && (xcol < WW);

    s16x8 af[2];
    const unsigned short* ap = wob + (size_t)ki * 1024;
#pragma unroll
    for (int i = 0; i < 2; ++i)
      af[i] = *(const s16x8*)&ap[(fq * 32 + i * 16 + fr) * 8];

    const float* bp = xb + (size_t)cc0 * HW + y * WW + xcol;
#pragma unroll
    for (int g = 0; g < 4; ++g) {
      s16x8 v;
#pragma unroll
      for (int j = 0; j < 8; ++j) {
        float val = ok ? bp[(size_t)(g * 8 + j) * HW] : 0.f;
        v[j] = (short)f2bf(val);
      }
      *(s16x8*)&sb[(g * 64 + lane) * 8] = v;
    }
    __builtin_amdgcn_s_waitcnt(0);

    s16x8 bf[4];
#pragma unroll
    for (int jn = 0; jn < 4; ++jn)
      bf[jn] = *(const s16x8*)&sb[(fq * 64 + jn * 16 + fr) * 8];
#pragma unroll
    for (int i = 0; i < 2; ++i)
#pragma unroll
      for (int jn = 0; jn < 4; ++jn)
        acc[i][jn] = __builtin_amdgcn_mfma_f32_16x16x32_bf16(af[i], bf[jn], acc[i][jn], 0, 0, 0);
  }

  __syncthreads();
#pragma unroll
  for (int i = 0; i < 2; ++i)
#pragma unroll
    for (int jn = 0; jn < 4; ++jn)
#pragma unroll
      for (int rg = 0; rg < 4; ++rg)
        red[wv * 2048 + (i * 16 + fq * 4 + rg) * 64 + jn * 16 + fr] = acc[i][jn][rg];
  __syncthreads();

  const int m = t >> 3;
  const int pq = (t & 7) * 8;
  float4 v0 = make_float4(0.f, 0.f, 0.f, 0.f), v1 = v0;
#pragma unroll
  for (int w = 0; w < 4; ++w) {
    float4 a = *(float4*)&red[w * 2048 + m * 64 + pq];
    float4 c = *(float4*)&red[w * 2048 + m * 64 + pq + 4];
    v0.x += a.x; v0.y += a.y; v0.z += a.z; v0.w += a.w;
    v1.x += c.x; v1.y += c.y; v1.z += c.z; v1.w += c.w;
  }
  if (m < OC) {
    float bo = b_off[m];
    v0.x += bo; v0.y += bo; v0.z += bo; v0.w += bo;
    v1.x += bo; v1.y += bo; v1.z += bo; v1.w += bo;
    float* op = off_ws + ((size_t)b * OC + m) * HW + h * WW + pq;
    *(float4*)op = v0;
    *(float4*)(op + 4) = v1;
  }
}

// ---------------- Kernel W0: pack w -> bf16 k-major image ----------------
__global__ __launch_bounds__(256) void wtrans_kernel(
    const float* __restrict__ w, unsigned short* __restrict__ wTb) {
  const int kb = blockIdx.x;          // 0..71
  const int kk = kb >> 3;
  const int c0 = (kb & 7) << 5;
  const int o = threadIdx.x;
#pragma unroll
  for (int g = 0; g < 4; ++g)
#pragma unroll
    for (int j = 0; j < 8; ++j) {
      int c = c0 + g * 8 + j;
      wTb[(((size_t)kb * 4 + g) * 256 + o) * 8 + j] =
          f2bf(w[((size_t)o * CIN + c) * 9 + kk]);
    }
}

// ---------------- Kernel B: barrier-free gather-GEMM, 1 wave per block ----------------
// grid 2048: b = bx&7 (XCD affinity), pixel-tile pt = bx>>3 (16 px).
// Lane = (pl = lane&15 -> pixel, fq = lane>>4 -> k-octet quad): the MFMA B-fragment
// layout B[n=lane&15][k=fq*8+j] IS the per-lane gather set -> B built in registers,
// no LDS, no __syncthreads. A frags global->VGPR (wTb L2-resident). Gathers
// prefetched 1 iter ahead (no barrier to drain them).
__global__ __launch_bounds__(64, 2) void gemm_kernel(
    const float* __restrict__ x, const unsigned short* __restrict__ wTb,
    const float* __restrict__ off_ws, const float* __restrict__ bias,
    float* __restrict__ out) {
  const int lane = threadIdx.x;
  const int b = blockIdx.x & 7;
  const int pt = blockIdx.x >> 3;
  const int p0 = pt << 4;
  const int pl = lane & 15;
  const int fq = lane >> 4;
  const int p = p0 + pl;
  const int h = p >> 6, w_ = p & 63;
  const float* xb = x + (size_t)b * CIN * HW;

  f32x4 acc[16] = {};

  int jA, jB;                       // byte offsets of the two float2 corner-pairs
  float wAlo, wAhi, wBlo, wBhi;     // folded bilinear/clamp weights

  auto comp_idx = [&](int kk) {
    float dy = off_ws[((size_t)b * OC + 2 * kk) * HW + p];
    float dx = off_ws[((size_t)b * OC + 2 * kk + 1) * HW + p];
    float py = (float)(kk / 3 - 1 + h) + dy;
    float px = (float)(kk % 3 - 1 + w_) + dx;
    float y0f = floorf(py), x0f = floorf(px);
    float fy = py - y0f, fx = px - x0f;
    int y0 = (int)y0f, x0 = (int)x0f;
    int y1 = y0 + 1, x1 = x0 + 1;
    bool vy0 = (y0 >= 0) && (y0 < HH), vy1 = (y1 >= 0) && (y1 < HH);
    bool vx0 = (x0 >= 0) && (x0 < WW), vx1 = (x1 >= 0) && (x1 < WW);
    int cy0 = min(max(y0, 0), HH - 1), cy1 = min(max(y1, 0), HH - 1);
    int cx0 = min(max(x0, 0), WW - 1), cx1 = min(max(x1, 0), WW - 1);
    float q0 = (vy0 && vx0) ? (1.f - fy) * (1.f - fx) : 0.f;
    float q1 = (vy0 && vx1) ? (1.f - fy) * fx : 0.f;
    float q2 = (vy1 && vx0) ? fy * (1.f - fx) : 0.f;
    float q3 = (vy1 && vx1) ? fy * fx : 0.f;
    int bc = min(cx0, WW - 2);      // pair base column: loads [bc, bc+1], never OOB
    wAlo = (cx0 == bc ? q0 : 0.f) + (cx1 == bc ? q1 : 0.f);
    wAhi = (q0 + q1) - wAlo;
    wBlo = (cx0 == bc ? q2 : 0.f) + (cx1 == bc ? q3 : 0.f);
    wBhi = (q2 + q3) - wBlo;
    jA = (cy0 * WW + bc) * 4;
    jB = (cy1 * WW + bc) * 4;
  };

  auto gather = [&](int c0, f32x2* gA, f32x2* gB) {
    const char* bp = (const char*)xb + (size_t)(c0 + fq * 8) * (HW * 4);
#pragma unroll
    for (int j = 0; j < 8; ++j) {
      __builtin_memcpy(&gA[j], bp + jA, 8);
      __builtin_memcpy(&gB[j], bp + jB, 8);
      bp += HW * 4;
    }
  };

  f32x2 rA[8], rB[8], nA[8], nB[8];
  comp_idx(0);
  gather(0, rA, rB);

  for (int iter = 0; iter < 72; ++iter) {
    // A fragments: 16 x dwordx4 straight from global (L2-resident image)
    s16x8 af[16];
#pragma unroll
    for (int m = 0; m < 16; ++m)
      af[m] = *(const s16x8*)&wTb[(((size_t)iter * 4 + fq) * 256 + m * 16 + pl) * 8];

    // combine previously-gathered corners -> B fragment (uses current kk weights)
    s16x8 bfr;
#pragma unroll
    for (int j = 0; j < 8; ++j) {
      float val = wAlo * rA[j].x + wAhi * rA[j].y + wBlo * rB[j].x + wBhi * rB[j].y;
      bfr[j] = (short)f2bf(val);
    }

    // prefetch next iter's gathers (after combine: weights may be rewritten here)
    const int nxt = iter + 1;
    if (nxt < 72) {
      if ((nxt & 7) == 0) comp_idx(nxt >> 3);
      gather((nxt & 7) << 5, nA, nB);
    }

#pragma unroll
    for (int m = 0; m < 16; ++m)
      acc[m] = __builtin_amdgcn_mfma_f32_16x16x32_bf16(af[m], bfr, acc[m], 0, 0, 0);

#pragma unroll
    for (int j = 0; j < 8; ++j) { rA[j] = nA[j]; rB[j] = nB[j]; }
  }

  // epilogue: + bias, store fp32
#pragma unroll
  for (int m = 0; m < 16; ++m) {
#pragma unroll
    for (int rg = 0; rg < 4; ++rg) {
      int o = m * 16 + fq * 4 + rg;
      out[((size_t)(b * COUT + o)) * HW + p] = acc[m][rg] + bias[o];
    }
  }
}

// ---------------- Kernel C: per-channel sum/sumsq ----------------
__global__ __launch_bounds__(256) void stats_kernel(
    const float* __restrict__ out, float* __restrict__ stats) {
  const int o = blockIdx.x, b = blockIdx.y;
  const float* p = out + ((size_t)(b * COUT + o)) * HW;
  float s = 0.f, s2 = 0.f;
  for (int i = threadIdx.x * 4; i < HW; i += 1024) {
    float4 v = *(const float4*)(p + i);
    s += v.x + v.y + v.z + v.w;
    s2 += v.x * v.x + v.y * v.y + v.z * v.z + v.w * v.w;
  }
#pragma unroll
  for (int off = 32; off > 0; off >>= 1) {
    s += __shfl_down(s, off);
    s2 += __shfl_down(s2, off);
  }
  __shared__ float ps[4], ps2[4];
  int wid = threadIdx.x >> 6;
  if ((threadIdx.x & 63) == 0) { ps[wid] = s; ps2[wid] = s2; }
  __syncthreads();
  if (threadIdx.x == 0) {
    atomicAdd(&stats[o], ps[0] + ps[1] + ps[2] + ps[3]);
    atomicAdd(&stats[COUT + o], ps2[0] + ps2[1] + ps2[2] + ps2[3]);
  }
}

// ---------------- Kernel D: normalize + ReLU in-place ----------------
__global__ __launch_bounds__(256) void bn_kernel(
    float* __restrict__ out, const float* __restrict__ stats,
    const float* __restrict__ gamma, const float* __restrict__ beta) {
  int i4 = (blockIdx.x * 256 + threadIdx.x) * 4;
  int o = (i4 >> 12) & (COUT - 1);
  const float inv_n = 1.f / (float)(BN_ * HW);
  float mean = stats[o] * inv_n;
  float var = stats[COUT + o] * inv_n - mean * mean;
  float sc = gamma[o] * rsqrtf(var + EPS);
  float sh = beta[o] - mean * sc;
  float4 v = *(float4*)(out + i4);
  v.x = fmaxf(fmaf(v.x, sc, sh), 0.f);
  v.y = fmaxf(fmaf(v.y, sc, sh), 0.f);
  v.z = fmaxf(fmaf(v.z, sc, sh), 0.f);
  v.w = fmaxf(fmaf(v.w, sc, sh), 0.f);
  *(float4*)(out + i4) = v;
}

extern "C" void kernel_launch(void* const* d_in, const int* in_sizes, int n_in,
                              void* d_out, int out_size, void* d_ws, size_t ws_size,
                              hipStream_t stream) {
  const float* x     = (const float*)d_in[0];
  const float* w_off = (const float*)d_in[1];
  const float* b_off = (const float*)d_in[2];
  const float* w     = (const float*)d_in[3];
  const float* bias  = (const float*)d_in[4];
  const float* gamma = (const float*)d_in[5];
  const float* beta  = (const float*)d_in[6];
  float* out = (float*)d_out;
  float* ws = (float*)d_ws;
  float* off_ws = ws + OFF_WS;
  unsigned short* wTb = (unsigned short*)(ws + WTB_WS);
  unsigned short* wob = (unsigned short*)(ws + WOB_WS);
  float* stats = ws + ST_WS;

  hipMemsetAsync(stats, 0, 2 * COUT * sizeof(float), stream);
  wob_kernel<<<72, 256, 0, stream>>>(w_off, wob);
  wtrans_kernel<<<72, 256, 0, stream>>>(w, wTb);
  offset_kernel<<<512, 256, 0, stream>>>(x, wob, b_off, off_ws);
  gemm_kernel<<<2048, 64, 0, stream>>>(x, wTb, off_ws, bias, out);
  stats_kernel<<<dim3(COUT, BN_), 256, 0, stream>>>(out, stats);
  bn_kernel<<<NTOT / 1024, 256, 0, stream>>>(out, stats, gamma, beta);
}

// Round 7
// 331.398 us; speedup vs baseline: 3.7204x; 1.1249x over previous
//
#include <hip/hip_runtime.h>
#include <math.h>

#define BN_ 8
#define CIN 256
#define COUT 256
#define HH 64
#define WW 64
#define HW 4096
#define KK 9
#define OC 18
#define EPS 1e-5f
#define NTOT (BN_ * COUT * HW)

// ws layout (float units):
//   off_ws: [B][18][HW]                 = 589824 floats
//   wTb:    bf16 [72][4][256][8] shorts = 294912 floats (main GEMM A image)
//   wob:    bf16 [72][4][32][8] shorts  = 36864 floats  (offset-conv A image)
//   stats:  [2][COUT]                   = 512 floats
//   xt:     bf16 [B][HW][256] shorts    = 4194304 floats (channel-last x)
#define OFF_WS 0
#define WTB_WS 589824
#define WOB_WS 884736
#define ST_WS  921600
#define XT_WS  922112

typedef float f32x4 __attribute__((ext_vector_type(4)));
typedef short s16x8 __attribute__((ext_vector_type(8)));

__device__ __forceinline__ unsigned short f2bf(float f) {
  unsigned int u = __float_as_uint(f);
  unsigned int r = (u + 0x7fffu + ((u >> 16) & 1u)) >> 16;  // RNE
  return (unsigned short)r;
}
__device__ __forceinline__ float bf2f(short s) {
  return __uint_as_float(((unsigned int)(unsigned short)s) << 16);
}

// ---------------- Kernel T: transpose x -> xt[b][p][c] bf16 ----------------
// grid (HW/64, CIN/64, B), block 256. LDS tile stored transposed [px][c].
__global__ __launch_bounds__(256) void xpose_kernel(
    const float* __restrict__ x, unsigned short* __restrict__ xt) {
  __shared__ float s[64][65];
  const int t = threadIdx.x;
  const int p0 = blockIdx.x * 64;
  const int c0 = blockIdx.y * 64;
  const int b  = blockIdx.z;
  const float* xb = x + ((size_t)b * CIN + c0) * HW + p0;
#pragma unroll
  for (int pass = 0; pass < 4; ++pass) {
    int cr = pass * 16 + (t >> 4);
    int ps = (t & 15) * 4;
    float4 v = *(const float4*)(xb + (size_t)cr * HW + ps);
    s[ps + 0][cr] = v.x; s[ps + 1][cr] = v.y; s[ps + 2][cr] = v.z; s[ps + 3][cr] = v.w;
  }
  __syncthreads();
  unsigned short* xo = xt + ((size_t)b * HW + p0) * 256 + c0;
#pragma unroll
  for (int r = 0; r < 2; ++r) {
    int flat = r * 256 + t;
    int pr = flat >> 3, sub = flat & 7;
    s16x8 v;
#pragma unroll
    for (int j = 0; j < 8; ++j) v[j] = (short)f2bf(s[pr][sub * 8 + j]);
    *(s16x8*)(xo + (size_t)pr * 256 + sub * 8) = v;
  }
}

// ---------------- Kernel W1: pack w_off -> bf16 fragment image (M=32 pad) ----------------
__global__ __launch_bounds__(256) void wob_kernel(
    const float* __restrict__ w_off, unsigned short* __restrict__ wob) {
  const int ki = blockIdx.x;          // 0..71
  const int kk = ki >> 3;
  const int cc0 = (ki & 7) << 5;
#pragma unroll
  for (int r = 0; r < 4; ++r) {
    int e = r * 256 + threadIdx.x;    // g*256 + m*8 + j
    int g = e >> 8, m = (e >> 3) & 31, j = e & 7;
    int c = cc0 + g * 8 + j;
    unsigned short v = 0;
    if (m < OC) v = f2bf(w_off[((size_t)m * CIN + c) * 9 + kk]);
    wob[(size_t)ki * 1024 + e] = v;
  }
}

// ---------------- Kernel A: offset conv as MFMA GEMM, K-split across waves ----------------
__global__ __launch_bounds__(256) void offset_kernel(
    const float* __restrict__ x, const unsigned short* __restrict__ wob,
    const float* __restrict__ b_off, float* __restrict__ off_ws) {
  __shared__ __align__(16) char smem[32768];
  const int t = threadIdx.x;
  const int lane = t & 63;
  const int wv = t >> 6;
  const int b = blockIdx.x & 7;
  const int h = blockIdx.x >> 3;
  const float* xb = x + (size_t)b * CIN * HW;
  const int fr = lane & 15, fq = lane >> 4;
  unsigned short* sb = (unsigned short*)smem + wv * 2048;
  float* red = (float*)smem;

  f32x4 acc[2][4] = {};

  for (int s = 0; s < 18; ++s) {
    const int ki = wv * 18 + s;
    const int kk = ki >> 3, cc0 = (ki & 7) << 5;
    const int ky = kk / 3 - 1, kx = kk % 3 - 1;
    const int y = h + ky;
    const bool yok = (y >= 0) && (y < HH);
    const int xcol = lane + kx;
    const bool ok = yok && (xcol >= 0) && (xcol < WW);

    s16x8 af[2];
    const unsigned short* ap = wob + (size_t)ki * 1024;
#pragma unroll
    for (int i = 0; i < 2; ++i)
      af[i] = *(const s16x8*)&ap[(fq * 32 + i * 16 + fr) * 8];

    const float* bp = xb + (size_t)cc0 * HW + y * WW + xcol;
#pragma unroll
    for (int g = 0; g < 4; ++g) {
      s16x8 v;
#pragma unroll
      for (int j = 0; j < 8; ++j) {
        float val = ok ? bp[(size_t)(g * 8 + j) * HW] : 0.f;
        v[j] = (short)f2bf(val);
      }
      *(s16x8*)&sb[(g * 64 + lane) * 8] = v;
    }
    __builtin_amdgcn_s_waitcnt(0);

    s16x8 bf[4];
#pragma unroll
    for (int jn = 0; jn < 4; ++jn)
      bf[jn] = *(const s16x8*)&sb[(fq * 64 + jn * 16 + fr) * 8];
#pragma unroll
    for (int i = 0; i < 2; ++i)
#pragma unroll
      for (int jn = 0; jn < 4; ++jn)
        acc[i][jn] = __builtin_amdgcn_mfma_f32_16x16x32_bf16(af[i], bf[jn], acc[i][jn], 0, 0, 0);
  }

  __syncthreads();
#pragma unroll
  for (int i = 0; i < 2; ++i)
#pragma unroll
    for (int jn = 0; jn < 4; ++jn)
#pragma unroll
      for (int rg = 0; rg < 4; ++rg)
        red[wv * 2048 + (i * 16 + fq * 4 + rg) * 64 + jn * 16 + fr] = acc[i][jn][rg];
  __syncthreads();

  const int m = t >> 3;
  const int pq = (t & 7) * 8;
  float4 v0 = make_float4(0.f, 0.f, 0.f, 0.f), v1 = v0;
#pragma unroll
  for (int w = 0; w < 4; ++w) {
    float4 a = *(float4*)&red[w * 2048 + m * 64 + pq];
    float4 c = *(float4*)&red[w * 2048 + m * 64 + pq + 4];
    v0.x += a.x; v0.y += a.y; v0.z += a.z; v0.w += a.w;
    v1.x += c.x; v1.y += c.y; v1.z += c.z; v1.w += c.w;
  }
  if (m < OC) {
    float bo = b_off[m];
    v0.x += bo; v0.y += bo; v0.z += bo; v0.w += bo;
    v1.x += bo; v1.y += bo; v1.z += bo; v1.w += bo;
    float* op = off_ws + ((size_t)b * OC + m) * HW + h * WW + pq;
    *(float4*)op = v0;
    *(float4*)(op + 4) = v1;
  }
}

// ---------------- Kernel W0: pack w -> bf16 k-major image ----------------
__global__ __launch_bounds__(256) void wtrans_kernel(
    const float* __restrict__ w, unsigned short* __restrict__ wTb) {
  const int kb = blockIdx.x;          // 0..71
  const int kk = kb >> 3;
  const int c0 = (kb & 7) << 5;
  const int o = threadIdx.x;
#pragma unroll
  for (int g = 0; g < 4; ++g)
#pragma unroll
    for (int j = 0; j < 8; ++j) {
      int c = c0 + g * 8 + j;
      wTb[(((size_t)kb * 4 + g) * 256 + o) * 8 + j] =
          f2bf(w[((size_t)o * CIN + c) * 9 + kk]);
    }
}

// ---------------- Kernel B: channel-last gather MFMA GEMM + fused stats ----------------
// grid 512: b = bx&7 (XCD), h = bx>>3 (64-px row tile). Block 256 = 4 waves.
// Gathers hit xt[b][p][c] (channel-last bf16): one 16B load = 8 channels of a
// corner -> 4 loads per (pixel, 32ch chunk) vs 32 channel-strided before.
#define SA_SZ 8192   // shorts: 4*256*8
#define SB_SZ 2048   // shorts: 4*64*8

__global__ __launch_bounds__(256) void gemm_kernel(
    const unsigned short* __restrict__ xt, const unsigned short* __restrict__ wTb,
    const float* __restrict__ off_ws, const float* __restrict__ bias,
    float* __restrict__ out, float* __restrict__ stats) {
  __shared__ unsigned short s_a[2][SA_SZ];
  __shared__ unsigned short s_b[2][SB_SZ];
  const int t = threadIdx.x;
  const int lane = t & 63;
  const int wv = t >> 6;
  const int b = blockIdx.x & 7;
  const int h = blockIdx.x >> 3;
  const int p0 = h * 64;
  const int px = t & 63;               // gather pixel
  const int oct = t >> 6;              // channel octet (8ch) within 32-chunk
  const int fr = lane & 15, fq = lane >> 4;
  const unsigned short* xtb = xt + (size_t)b * HW * 256;

  int cofs[4];     // corner byte offsets: (cy*WW+cx)*512
  float qw[4];

  auto comp_idx = [&](int kk) {
    float dy = off_ws[((size_t)b * OC + 2 * kk) * HW + p0 + px];
    float dx = off_ws[((size_t)b * OC + 2 * kk + 1) * HW + p0 + px];
    float py = (float)(kk / 3 - 1 + h) + dy;
    float pxf = (float)(kk % 3 - 1 + px) + dx;
    float y0f = floorf(py), x0f = floorf(pxf);
    float fy = py - y0f, fx = pxf - x0f;
    int y0 = (int)y0f, x0 = (int)x0f;
    int y1 = y0 + 1, x1 = x0 + 1;
    bool vy0 = (y0 >= 0) && (y0 < HH), vy1 = (y1 >= 0) && (y1 < HH);
    bool vx0 = (x0 >= 0) && (x0 < WW), vx1 = (x1 >= 0) && (x1 < WW);
    int cy0 = min(max(y0, 0), HH - 1), cy1 = min(max(y1, 0), HH - 1);
    int cx0 = min(max(x0, 0), WW - 1), cx1 = min(max(x1, 0), WW - 1);
    cofs[0] = (cy0 * WW + cx0) * 512;  qw[0] = (vy0 && vx0) ? (1.f - fy) * (1.f - fx) : 0.f;
    cofs[1] = (cy0 * WW + cx1) * 512;  qw[1] = (vy0 && vx1) ? (1.f - fy) * fx : 0.f;
    cofs[2] = (cy1 * WW + cx0) * 512;  qw[2] = (vy1 && vx0) ? fy * (1.f - fx) : 0.f;
    cofs[3] = (cy1 * WW + cx1) * 512;  qw[3] = (vy1 && vx1) ? fy * fx : 0.f;
  };

  auto stage_a = [&](int iter, int buf) {
    const unsigned char* gb = (const unsigned char*)(wTb + (size_t)iter * SA_SZ);
    unsigned char* lb = (unsigned char*)s_a[buf];
#pragma unroll
    for (int i = 0; i < 4; ++i) {
      int chunk = (wv * 4 + i) * 1024;
      __builtin_amdgcn_global_load_lds(
          (const __attribute__((address_space(1))) unsigned char*)(gb + chunk + lane * 16),
          (__attribute__((address_space(3))) unsigned char*)(lb + chunk),
          16, 0, 0);
    }
  };

  s16x8 g[4];
  auto gather = [&](int c0) {
    const char* bp = (const char*)xtb + (size_t)(c0 + oct * 8) * 2;
#pragma unroll
    for (int k = 0; k < 4; ++k)
      __builtin_memcpy(&g[k], bp + cofs[k], 16);
  };

  auto combine_write = [&](int buf) {
    s16x8 v;
#pragma unroll
    for (int j = 0; j < 8; ++j) {
      float val = 0.f;
#pragma unroll
      for (int k = 0; k < 4; ++k)
        val = fmaf(qw[k], bf2f(g[k][j]), val);
      v[j] = (short)f2bf(val);
    }
    *(s16x8*)&s_b[buf][(oct * 64 + px) * 8] = v;
  };

  f32x4 acc[4][4] = {};

  // prologue
  comp_idx(0);
  stage_a(0, 0);
  gather(0);
  combine_write(0);
  __syncthreads();

  for (int iter = 0; iter < 72; ++iter) {
    const int cur = iter & 1;
    s16x8 af[4], bfr[4];
#pragma unroll
    for (int i = 0; i < 4; ++i)
      af[i] = *(const s16x8*)&s_a[cur][((fq * 256) + wv * 64 + i * 16 + fr) * 8];
#pragma unroll
    for (int j = 0; j < 4; ++j)
      bfr[j] = *(const s16x8*)&s_b[cur][((fq * 64) + j * 16 + fr) * 8];

    const int nxt = iter + 1;
    if (nxt < 72) {
      stage_a(nxt, cur ^ 1);
      if ((nxt & 7) == 0) comp_idx(nxt >> 3);
      gather((nxt & 7) << 5);
    }

#pragma unroll
    for (int i = 0; i < 4; ++i)
#pragma unroll
      for (int j = 0; j < 4; ++j)
        acc[i][j] = __builtin_amdgcn_mfma_f32_16x16x32_bf16(af[i], bfr[j], acc[i][j], 0, 0, 0);

    if (nxt < 72) combine_write(cur ^ 1);
    __syncthreads();
  }

  // epilogue: + bias, store, fused per-channel sum/sumsq
#pragma unroll
  for (int i = 0; i < 4; ++i) {
#pragma unroll
    for (int rg = 0; rg < 4; ++rg) {
      int o = wv * 64 + i * 16 + fq * 4 + rg;
      float bv = bias[o];
      float* op = out + ((size_t)(b * COUT + o)) * HW + p0 + fr;
      float s = 0.f, s2 = 0.f;
#pragma unroll
      for (int j = 0; j < 4; ++j) {
        float val = acc[i][j][rg] + bv;
        op[j * 16] = val;
        s += val; s2 += val * val;
      }
#pragma unroll
      for (int m = 1; m < 16; m <<= 1) {
        s += __shfl_xor(s, m);
        s2 += __shfl_xor(s2, m);
      }
      if (fr == 0) {
        atomicAdd(&stats[o], s);
        atomicAdd(&stats[COUT + o], s2);
      }
    }
  }
}

// ---------------- Kernel D: normalize + ReLU in-place ----------------
__global__ __launch_bounds__(256) void bn_kernel(
    float* __restrict__ out, const float* __restrict__ stats,
    const float* __restrict__ gamma, const float* __restrict__ beta) {
  int i4 = (blockIdx.x * 256 + threadIdx.x) * 4;
  int o = (i4 >> 12) & (COUT - 1);
  const float inv_n = 1.f / (float)(BN_ * HW);
  float mean = stats[o] * inv_n;
  float var = stats[COUT + o] * inv_n - mean * mean;
  float sc = gamma[o] * rsqrtf(var + EPS);
  float sh = beta[o] - mean * sc;
  float4 v = *(float4*)(out + i4);
  v.x = fmaxf(fmaf(v.x, sc, sh), 0.f);
  v.y = fmaxf(fmaf(v.y, sc, sh), 0.f);
  v.z = fmaxf(fmaf(v.z, sc, sh), 0.f);
  v.w = fmaxf(fmaf(v.w, sc, sh), 0.f);
  *(float4*)(out + i4) = v;
}

extern "C" void kernel_launch(void* const* d_in, const int* in_sizes, int n_in,
                              void* d_out, int out_size, void* d_ws, size_t ws_size,
                              hipStream_t stream) {
  const float* x     = (const float*)d_in[0];
  const float* w_off = (const float*)d_in[1];
  const float* b_off = (const float*)d_in[2];
  const float* w     = (const float*)d_in[3];
  const float* bias  = (const float*)d_in[4];
  const float* gamma = (const float*)d_in[5];
  const float* beta  = (const float*)d_in[6];
  float* out = (float*)d_out;
  float* ws = (float*)d_ws;
  float* off_ws = ws + OFF_WS;
  unsigned short* wTb = (unsigned short*)(ws + WTB_WS);
  unsigned short* wob = (unsigned short*)(ws + WOB_WS);
  float* stats = ws + ST_WS;
  unsigned short* xt = (unsigned short*)(ws + XT_WS);

  hipMemsetAsync(stats, 0, 2 * COUT * sizeof(float), stream);
  xpose_kernel<<<dim3(64, 4, 8), 256, 0, stream>>>(x, xt);
  wob_kernel<<<72, 256, 0, stream>>>(w_off, wob);
  wtrans_kernel<<<72, 256, 0, stream>>>(w, wTb);
  offset_kernel<<<512, 256, 0, stream>>>(x, wob, b_off, off_ws);
  gemm_kernel<<<512, 256, 0, stream>>>(xt, wTb, off_ws, bias, out, stats);
  bn_kernel<<<NTOT / 1024, 256, 0, stream>>>(out, stats, gamma, beta);
}